// Round 6
// baseline (381.555 us; speedup 1.0000x reference)
//
#include <hip/hip_runtime.h>
#include <hip/hip_fp16.h>

// ---------------------------------------------------------------------------
// GCN 4-layer forward on MI355X (gfx950).
//   Preprocess (ZERO global atomics): LDS range histograms (8 ranges x 128
//     chunks, PACKED 16-bit counters -> 25KB LDS) + per-edge bucket rank ->
//     reduce+norms -> parallel hierarchical scan fused into cursor kernel ->
//     single-pass CSR scatter. Chunk-co-located XCD swizzle for edge L2 reuse.
//     Weight split rides as extra blocks on k_hist's grid.
//   Per layer : bf16-split MFMA GEMM (3-term, ~fp32 precision), LDS-FREE:
//     B is 64-128KB -> L2-resident; fragments loaded directly from global
//     (bit-identical bytes to the old swizzled-LDS read). No barriers at all.
//     h in fp16 -> CSR gather with 16-lane/16B row segments (4 nodes/wave),
//     fused epilogue + bf16 hi/lo split.
// ---------------------------------------------------------------------------

typedef __attribute__((ext_vector_type(8))) short short8;
typedef __attribute__((ext_vector_type(4))) float f32x4;

#define NRANGE 8
#define NCHUNK 128
#define RMAX   6272   // 8*6272 = 50176 >= 50000 nodes; LDS = 2*(6272/2)*4 = 25088 B

__device__ inline unsigned short bf16_rne(float v) {
    union { float f; unsigned u; } c; c.f = v;
    unsigned u = c.u;
    unsigned lsb = (u >> 16) & 1u;
    u += 0x7fffu + lsb;
    return (unsigned short)(u >> 16);
}
__device__ inline float bf16_to_f(unsigned short h) {
    union { unsigned u; float f; } c; c.u = ((unsigned)h) << 16;
    return c.f;
}
__device__ inline void split_bf16(float v, unsigned short& hi, unsigned short& lo) {
    hi = bf16_rne(v);
    lo = bf16_rne(v - bf16_to_f(hi));
}

// ---------------------------------------------------------------------------
// Preprocessing — LDS-privatized histograms, packed 16-bit counters.
// ---------------------------------------------------------------------------

__global__ __launch_bounds__(256) void k_hist(const int* __restrict__ src,
                                              const int* __restrict__ dst,
                                              int ne, int R, int E,
                                              unsigned short* __restrict__ cnt_s,
                                              unsigned short* __restrict__ cnt_d,
                                              unsigned short* __restrict__ pos,
                                              const float* __restrict__ W0,
                                              const float* __restrict__ W1,
                                              const float* __restrict__ W2,
                                              const float* __restrict__ W3,
                                              unsigned short* __restrict__ Wh0, unsigned short* __restrict__ Wl0,
                                              unsigned short* __restrict__ Wh1, unsigned short* __restrict__ Wl1,
                                              unsigned short* __restrict__ Wh2, unsigned short* __restrict__ Wl2,
                                              unsigned short* __restrict__ Wh3, unsigned short* __restrict__ Wl3) {
    __shared__ int hs32[RMAX / 2];
    __shared__ int hd32[RMAX / 2];
    if (blockIdx.x >= NRANGE * NCHUNK) {
        // ---- weight split tail blocks (288 blocks x 256 = 73728 elements) ----
        int i = (blockIdx.x - NRANGE * NCHUNK) * 256 + threadIdx.x;
        const float* W; unsigned short *Wh, *Wl; int K, F, off;
        if (i < 32768)                     { W = W0; Wh = Wh0; Wl = Wl0; K = 256; F = 128; off = i; }
        else if (i < 32768 + 16384)        { W = W1; Wh = Wh1; Wl = Wl1; K = 128; F = 128; off = i - 32768; }
        else if (i < 32768 + 32768)        { W = W2; Wh = Wh2; Wl = Wl2; K = 128; F = 128; off = i - 49152; }
        else if (i < 32768 + 32768 + 8192) { W = W3; Wh = Wh3; Wl = Wl3; K = 128; F = 64;  off = i - 65536; }
        else return;
        int k = off / F, c = off % F;
        unsigned short h, l;
        split_bf16(W[k * F + c], h, l);
        Wh[c * K + k] = h;
        Wl[c * K + k] = l;
        return;
    }
    // chunk-major decode: c = bid % NCHUNK -> XCD = c % 8 (NCHUNK % 8 == 0),
    // so all 8 range-blocks of a chunk share one XCD's L2 for the edge reads.
    int c = blockIdx.x & (NCHUNK - 1);
    int r = blockIdx.x >> 7;
    int tid = threadIdx.x;
    int Rh = R >> 1;
    for (int i = tid; i < Rh; i += 256) { hs32[i] = 0; hd32[i] = 0; }
    __syncthreads();
    int lo = r * R;
    int e0 = c * E, e1 = min(e0 + E, ne);
    for (int i = e0 + tid; i < e1; i += 256) {
        int s = src[i], d = dst[i];
        unsigned ps = (unsigned)(s - lo);
        unsigned pd = (unsigned)(d - lo);
        if (ps < (unsigned)R)
            atomicAdd(&hs32[ps >> 1], 1 << ((ps & 1) << 4));
        if (pd < (unsigned)R) {
            int sh = (pd & 1) << 4;
            int old = atomicAdd(&hd32[pd >> 1], 1 << sh);
            pos[i] = (unsigned short)((old >> sh) & 0xffff);   // rank in bucket
        }
    }
    __syncthreads();
    int base2 = (r * NCHUNK + c) * Rh;
    int* cs32 = (int*)cnt_s;
    int* cd32 = (int*)cnt_d;
    for (int i = tid; i < Rh; i += 256) {
        cs32[base2 + i] = hs32[i];
        cd32[base2 + i] = hd32[i];
    }
}

// Reduce per-node degrees + norms, AND emit per-block (256-node) degree sums
// for the hierarchical scan. Grid must be exactly (NRANGE*R)/256 blocks.
__global__ __launch_bounds__(256) void k_reduce_norms(const unsigned short* __restrict__ cnt_s,
                                                      const unsigned short* __restrict__ cnt_d,
                                                      int R, int n,
                                                      float* __restrict__ onrm,
                                                      float* __restrict__ inrm,
                                                      int* __restrict__ degd_sum,
                                                      int* __restrict__ blocksum) {
    __shared__ int red[256];
    int tid = threadIdx.x;
    int i = blockIdx.x * 256 + tid;
    int r = i / R, ip = i - r * R;
    int ds = 0, dd = 0;
    for (int c = 0; c < NCHUNK; ++c) {
        ds += cnt_s[(r * NCHUNK + c) * R + ip];
        dd += cnt_d[(r * NCHUNK + c) * R + ip];
    }
    degd_sum[i] = dd;
    if (i < n) {
        onrm[i] = rsqrtf((float)max(ds, 1));
        inrm[i] = rsqrtf((float)max(dd, 1));
    }
    // block-wide sum of dd
    red[tid] = dd;
    __syncthreads();
#pragma unroll
    for (int off = 128; off > 0; off >>= 1) {
        if (tid < off) red[tid] += red[tid + off];
        __syncthreads();
    }
    if (tid == 0) blocksum[blockIdx.x] = red[0];
}

// Fused parallel scan + cursor bases.
__global__ __launch_bounds__(256) void k_cursors2(const int* __restrict__ blocksum, int nblk,
                                                  const int* __restrict__ degd_sum,
                                                  const unsigned short* __restrict__ cnt_d, int R,
                                                  int* __restrict__ row_ptr,
                                                  int* __restrict__ cbase, int total_i) {
    __shared__ int bs[256];
    __shared__ int wsum[4];
    int tid = threadIdx.x;
    bs[tid] = (tid < nblk) ? blocksum[tid] : 0;
    __syncthreads();
#pragma unroll
    for (int off = 1; off < 256; off <<= 1) {
        int v = bs[tid];
        int u = (tid >= off) ? bs[tid - off] : 0;
        __syncthreads();
        bs[tid] = v + u;
        __syncthreads();
    }
    int base = (blockIdx.x > 0) ? bs[blockIdx.x - 1] : 0;

    int i = blockIdx.x * 256 + tid;
    int dd = degd_sum[i];
    int lane = tid & 63, wid = tid >> 6;
    int x = dd;
#pragma unroll
    for (int off = 1; off < 64; off <<= 1) {
        int y = __shfl_up(x, off, 64);
        if (lane >= off) x += y;
    }
    if (lane == 63) wsum[wid] = x;
    __syncthreads();
    int wbase = 0;
    for (int wp = 0; wp < wid; ++wp) wbase += wsum[wp];
    int excl = base + wbase + (x - dd);
    row_ptr[i] = excl;
    if (i == total_i - 1) row_ptr[total_i] = excl + dd;

    int r = i / R, ip = i - r * R;
    int run = excl;
    for (int c = 0; c < NCHUNK; ++c) {
        int idx = (r * NCHUNK + c) * R + ip;
        cbase[idx] = run;
        run += cnt_d[idx];
    }
}

__global__ void k_csr_scatter(const int* __restrict__ src,
                              const int* __restrict__ dst,
                              const unsigned short* __restrict__ pos,
                              const int* __restrict__ cbase,
                              int ne, int R, int E,
                              int* __restrict__ eidx) {
    int i = blockIdx.x * blockDim.x + threadIdx.x;
    if (i >= ne) return;
    int d = dst[i];
    int r = d / R, ip = d - r * R;
    int c = i / E;
    eidx[cbase[(r * NCHUNK + c) * R + ip] + pos[i]] = src[i];
}

// ---------------------------------------------------------------------------
// Weight split (standalone — only used on the legacy preprocessing path)
// ---------------------------------------------------------------------------

__global__ void k_split_w_all(const float* __restrict__ W0, const float* __restrict__ W1,
                              const float* __restrict__ W2, const float* __restrict__ W3,
                              unsigned short* __restrict__ Wh0, unsigned short* __restrict__ Wl0,
                              unsigned short* __restrict__ Wh1, unsigned short* __restrict__ Wl1,
                              unsigned short* __restrict__ Wh2, unsigned short* __restrict__ Wl2,
                              unsigned short* __restrict__ Wh3, unsigned short* __restrict__ Wl3) {
    int i = blockIdx.x * blockDim.x + threadIdx.x;
    const float* W; unsigned short *Wh, *Wl; int K, F, off;
    if (i < 32768)                    { W = W0; Wh = Wh0; Wl = Wl0; K = 256; F = 128; off = i; }
    else if (i < 32768 + 16384)       { W = W1; Wh = Wh1; Wl = Wl1; K = 128; F = 128; off = i - 32768; }
    else if (i < 32768 + 32768)       { W = W2; Wh = Wh2; Wl = Wl2; K = 128; F = 128; off = i - 49152; }
    else if (i < 32768 + 32768 + 8192){ W = W3; Wh = Wh3; Wl = Wl3; K = 128; F = 64;  off = i - 65536; }
    else return;
    int k = off / F, c = off % F;
    unsigned short h, l;
    split_bf16(W[k * F + c], h, l);
    Wh[c * K + k] = h;
    Wl[c * K + k] = l;
}

// ---------------------------------------------------------------------------
// MFMA GEMM: H[m][c] = sum_k A[m][k]*W[k][c]; H stored fp16.
// LDS-FREE: B (64-128KB) is L2-resident; each lane loads its 16B B-fragment
// directly from global (same bytes the old swizzled-LDS read produced).
// No __syncthreads anywhere -> waves are independent streams; the 16 B-loads
// per k0-step are hoisted ahead of the MFMA cluster for MLP.
// FA=true: A read from fp32 X, *onrm + bf16 split fused into fragment load.
// Per-acc MFMA k-order identical to all previous versions (bit-exact).
// ---------------------------------------------------------------------------
template <int K, int N, bool FA>
__global__ __launch_bounds__(256) void k_mm(const unsigned short* __restrict__ Ah,
                                            const unsigned short* __restrict__ Al,
                                            const float* __restrict__ Xf,
                                            const float* __restrict__ onrm,
                                            const unsigned short* __restrict__ Bh,
                                            const unsigned short* __restrict__ Bl,
                                            __half* __restrict__ H, int n) {
    constexpr int KT = 128;
    constexpr int NT = N / 16;
    constexpr int NKT = K / KT;

    int tid = threadIdx.x;
    int w = tid >> 6, lane = tid & 63;
    int quad = lane >> 4, l16 = lane & 15;
    int row_base = blockIdx.x * 128 + w * 32;

    int ar0 = row_base + l16;
    int ar1 = row_base + 16 + l16;
    if (ar0 >= n) ar0 = n - 1;
    if (ar1 >= n) ar1 = n - 1;

    float on0 = 0.f, on1 = 0.f;
    if (FA) { on0 = onrm[ar0]; on1 = onrm[ar1]; }

    f32x4 acc[2][NT];
#pragma unroll
    for (int m = 0; m < 2; ++m)
#pragma unroll
        for (int t = 0; t < NT; ++t) acc[m][t] = (f32x4){0.f, 0.f, 0.f, 0.f};

    for (int kt = 0; kt < NKT; ++kt) {
#pragma unroll
        for (int k0 = 0; k0 < KT; k0 += 32) {
            int eoff = kt * KT + k0 + quad * 8;   // byte-identical to old kt*KT + (k0+quad*8)
            short8 a0hv, a0lv, a1hv, a1lv;
            if (FA) {
                const float* x0 = Xf + (size_t)ar0 * K + eoff;
                const float* x1 = Xf + (size_t)ar1 * K + eoff;
                float4 p00 = *(const float4*)x0;
                float4 p01 = *(const float4*)(x0 + 4);
                float4 p10 = *(const float4*)x1;
                float4 p11 = *(const float4*)(x1 + 4);
                float e0[8] = {p00.x, p00.y, p00.z, p00.w, p01.x, p01.y, p01.z, p01.w};
                float e1[8] = {p10.x, p10.y, p10.z, p10.w, p11.x, p11.y, p11.z, p11.w};
#pragma unroll
                for (int q = 0; q < 8; ++q) {
                    unsigned short hh, ll;
                    split_bf16(e0[q] * on0, hh, ll);
                    a0hv[q] = (short)hh; a0lv[q] = (short)ll;
                    split_bf16(e1[q] * on1, hh, ll);
                    a1hv[q] = (short)hh; a1lv[q] = (short)ll;
                }
            } else {
                a0hv = *(const short8*)(Ah + (size_t)ar0 * K + eoff);
                a0lv = *(const short8*)(Al + (size_t)ar0 * K + eoff);
                a1hv = *(const short8*)(Ah + (size_t)ar1 * K + eoff);
                a1lv = *(const short8*)(Al + (size_t)ar1 * K + eoff);
            }
            // hoist the 2*NT B-fragment loads (L2 hits) ahead of the MFMAs
            short8 bhv[NT], blv[NT];
#pragma unroll
            for (int t = 0; t < NT; ++t) {
                size_t cb = (size_t)(t * 16 + l16) * K + eoff;
                bhv[t] = *(const short8*)(Bh + cb);
                blv[t] = *(const short8*)(Bl + cb);
            }
#pragma unroll
            for (int t = 0; t < NT; ++t) {
                acc[0][t] = __builtin_amdgcn_mfma_f32_16x16x32_bf16(a0hv, bhv[t], acc[0][t], 0, 0, 0);
                acc[0][t] = __builtin_amdgcn_mfma_f32_16x16x32_bf16(a0lv, bhv[t], acc[0][t], 0, 0, 0);
                acc[0][t] = __builtin_amdgcn_mfma_f32_16x16x32_bf16(a0hv, blv[t], acc[0][t], 0, 0, 0);
                acc[1][t] = __builtin_amdgcn_mfma_f32_16x16x32_bf16(a1hv, bhv[t], acc[1][t], 0, 0, 0);
                acc[1][t] = __builtin_amdgcn_mfma_f32_16x16x32_bf16(a1lv, bhv[t], acc[1][t], 0, 0, 0);
                acc[1][t] = __builtin_amdgcn_mfma_f32_16x16x32_bf16(a1hv, blv[t], acc[1][t], 0, 0, 0);
            }
        }
    }

#pragma unroll
    for (int m = 0; m < 2; ++m) {
#pragma unroll
        for (int t = 0; t < NT; ++t) {
#pragma unroll
            for (int r = 0; r < 4; ++r) {
                int grow = row_base + m * 16 + quad * 4 + r;
                if (grow < n) H[(size_t)grow * N + t * 16 + l16] = __float2half(acc[m][t][r]);
            }
        }
    }
}

// ---------------------------------------------------------------------------
// Aggregation: 16-lane row segments, 4 nodes/wave (best-measured R2 config).
// ---------------------------------------------------------------------------

__global__ __launch_bounds__(256) void k_agg128_split(const __half* __restrict__ h,
                                                      const int* __restrict__ row_ptr,
                                                      const int* __restrict__ eidx,
                                                      const float* __restrict__ inrm,
                                                      const float* __restrict__ onrm,
                                                      const float* __restrict__ bias,
                                                      unsigned short* __restrict__ Ah,
                                                      unsigned short* __restrict__ Al, int n) {
    int wave = threadIdx.x >> 6;
    int lane = threadIdx.x & 63;
    int g = lane >> 4;
    int l = lane & 15;
    int node = blockIdx.x * 16 + wave * 4 + g;
    bool valid = node < n;
    int nd = valid ? node : n - 1;
    int beg = row_ptr[nd], end = row_ptr[nd + 1];
    const short8* h8 = (const short8*)h;   // row = 16 granules of 16B

    float a[4][8];
#pragma unroll
    for (int u = 0; u < 4; ++u)
#pragma unroll
        for (int c = 0; c < 8; ++c) a[u][c] = 0.f;

    int j = beg;
    for (; j + 4 <= end; j += 4) {
        int s[4];
#pragma unroll
        for (int u = 0; u < 4; ++u) s[u] = eidx[j + u];
        short8 v[4];
#pragma unroll
        for (int u = 0; u < 4; ++u) v[u] = h8[(size_t)s[u] * 16 + l];
#pragma unroll
        for (int u = 0; u < 4; ++u) {
            const __half2* ph = reinterpret_cast<const __half2*>(&v[u]);
#pragma unroll
            for (int p = 0; p < 4; ++p) {
                float2 f = __half22float2(ph[p]);
                a[u][2 * p] += f.x;
                a[u][2 * p + 1] += f.y;
            }
        }
    }
    for (; j < end; ++j) {
        short8 v = h8[(size_t)eidx[j] * 16 + l];
        const __half2* ph = reinterpret_cast<const __half2*>(&v);
#pragma unroll
        for (int p = 0; p < 4; ++p) {
            float2 f = __half22float2(ph[p]);
            a[0][2 * p] += f.x;
            a[0][2 * p + 1] += f.y;
        }
    }

    float nrm = inrm[nd];
    float on = onrm[nd];
    float4 b0 = ((const float4*)bias)[l * 2];
    float4 b1 = ((const float4*)bias)[l * 2 + 1];
    float bb[8] = {b0.x, b0.y, b0.z, b0.w, b1.x, b1.y, b1.z, b1.w};
    short8 hv, lv;
#pragma unroll
    for (int c = 0; c < 8; ++c) {
        float s = (a[0][c] + a[1][c]) + (a[2][c] + a[3][c]);
        float o = fmaxf(s * nrm + bb[c], 0.f) * on;
        unsigned short hh, ll;
        split_bf16(o, hh, ll);
        hv[c] = (short)hh;
        lv[c] = (short)ll;
    }
    if (valid) {
        ((short8*)Ah)[(size_t)node * 16 + l] = hv;
        ((short8*)Al)[(size_t)node * 16 + l] = lv;
    }
}

// FO=64 final layer: 16-lane x 8B segments (4 nodes/wave), unroll 8, fp32 out.
__global__ __launch_bounds__(256) void k_agg64(const __half* __restrict__ h,
                                               const int* __restrict__ row_ptr,
                                               const int* __restrict__ eidx,
                                               const float* __restrict__ inrm,
                                               const float* __restrict__ bias,
                                               float* __restrict__ out, int n) {
    int wave = threadIdx.x >> 6;
    int lane = threadIdx.x & 63;
    int g = lane >> 4;
    int l = lane & 15;
    int node = blockIdx.x * 16 + wave * 4 + g;
    bool valid = node < n;
    int nd = valid ? node : n - 1;
    int beg = row_ptr[nd], end = row_ptr[nd + 1];
    const ushort4* h4 = (const ushort4*)h;  // row = 16 granules of 8B

    float a[8][4];
#pragma unroll
    for (int u = 0; u < 8; ++u)
#pragma unroll
        for (int c = 0; c < 4; ++c) a[u][c] = 0.f;

    int j = beg;
    for (; j + 8 <= end; j += 8) {
        int s[8];
#pragma unroll
        for (int u = 0; u < 8; ++u) s[u] = eidx[j + u];
        ushort4 v[8];
#pragma unroll
        for (int u = 0; u < 8; ++u) v[u] = h4[(size_t)s[u] * 16 + l];
#pragma unroll
        for (int u = 0; u < 8; ++u) {
            const __half2* ph = reinterpret_cast<const __half2*>(&v[u]);
            float2 f0 = __half22float2(ph[0]);
            float2 f1 = __half22float2(ph[1]);
            a[u][0] += f0.x; a[u][1] += f0.y; a[u][2] += f1.x; a[u][3] += f1.y;
        }
    }
    for (; j < end; ++j) {
        ushort4 v = h4[(size_t)eidx[j] * 16 + l];
        const __half2* ph = reinterpret_cast<const __half2*>(&v);
        float2 f0 = __half22float2(ph[0]);
        float2 f1 = __half22float2(ph[1]);
        a[0][0] += f0.x; a[0][1] += f0.y; a[0][2] += f1.x; a[0][3] += f1.y;
    }

    float nrm = inrm[nd];
    float4 b4 = ((const float4*)bias)[l];
    float4 o;
    float s0 = ((a[0][0] + a[1][0]) + (a[2][0] + a[3][0])) + ((a[4][0] + a[5][0]) + (a[6][0] + a[7][0]));
    float s1 = ((a[0][1] + a[1][1]) + (a[2][1] + a[3][1])) + ((a[4][1] + a[5][1]) + (a[6][1] + a[7][1]));
    float s2 = ((a[0][2] + a[1][2]) + (a[2][2] + a[3][2])) + ((a[4][2] + a[5][2]) + (a[6][2] + a[7][2]));
    float s3 = ((a[0][3] + a[1][3]) + (a[2][3] + a[3][3])) + ((a[4][3] + a[5][3]) + (a[6][3] + a[7][3]));
    o.x = s0 * nrm + b4.x;
    o.y = s1 * nrm + b4.y;
    o.z = s2 * nrm + b4.z;
    o.w = s3 * nrm + b4.w;
    if (valid) ((float4*)out)[(size_t)node * 16 + l] = o;
}

// ---------------------------------------------------------------------------
// Legacy single-block scan (only for fallback path)
// ---------------------------------------------------------------------------
__global__ __launch_bounds__(1024) void k_scan(const int* __restrict__ deg, int n,
                                               int* __restrict__ row_ptr) {
    __shared__ int wsum[16];
    __shared__ int carry;
    int tid = threadIdx.x;
    int lane = tid & 63;
    int wid = tid >> 6;
    if (tid == 0) carry = 0;
    __syncthreads();
    int n4 = (n + 3) >> 2;
    for (int base = 0; base < n4; base += 1024) {
        int i4 = base + tid;
        int4 v = make_int4(0, 0, 0, 0);
        if (i4 < n4) v = ((const int4*)deg)[i4];
        int s = v.x + v.y + v.z + v.w;
        int x = s;
#pragma unroll
        for (int off = 1; off < 64; off <<= 1) {
            int y = __shfl_up(x, off, 64);
            if (lane >= off) x += y;
        }
        if (lane == 63) wsum[wid] = x;
        __syncthreads();
        if (wid == 0 && lane < 16) {
            int w = wsum[lane];
#pragma unroll
            for (int off = 1; off < 16; off <<= 1) {
                int y = __shfl_up(w, off, 16);
                if (lane >= off) w += y;
            }
            wsum[lane] = w;
        }
        __syncthreads();
        int excl = x - s + carry + (wid > 0 ? wsum[wid - 1] : 0);
        if (i4 < n4) {
            int e0 = excl, e1 = e0 + v.x, e2 = e1 + v.y, e3 = e2 + v.z;
            ((int4*)row_ptr)[i4] = make_int4(e0, e1, e2, e3);
        }
        __syncthreads();
        if (tid == 0) carry += wsum[15];
        __syncthreads();
    }
    if (tid == 0) row_ptr[n] = carry;
}

// ---------------------------------------------------------------------------
// Fallback fp32 path (known-good) — used if workspace too small for MFMA path.
// ---------------------------------------------------------------------------
template <int K, int FO, int TX, int TY, int RPT>
__global__ __launch_bounds__(256) void k_matmul(const float* __restrict__ X,
                                                const float* __restrict__ W,
                                                const float* __restrict__ onrm,
                                                float* __restrict__ H, int n) {
    constexpr int BROWS = TY * RPT;
    constexpr int LDK = K + 1;
    __shared__ float xs[BROWS * LDK];
    int tx = threadIdx.x, ty = threadIdx.y;
    int tid = ty * TX + tx;
    int row0 = blockIdx.x * BROWS;

    for (int idx = tid; idx < BROWS * K; idx += 256) {
        int r = idx / K;
        int k = idx - r * K;
        int row = row0 + r;
        xs[r * LDK + k] = (row < n) ? X[(size_t)row * K + k] : 0.f;
    }
    __syncthreads();

    float4 acc[RPT];
#pragma unroll
    for (int r = 0; r < RPT; ++r) acc[r] = make_float4(0.f, 0.f, 0.f, 0.f);

    const float4* W4 = (const float4*)W;
#pragma unroll 4
    for (int k = 0; k < K; ++k) {
        float4 w = W4[k * (FO / 4) + tx];
#pragma unroll
        for (int r = 0; r < RPT; ++r) {
            float xv = xs[(ty * RPT + r) * LDK + k];
            acc[r].x += xv * w.x;
            acc[r].y += xv * w.y;
            acc[r].z += xv * w.z;
            acc[r].w += xv * w.w;
        }
    }

#pragma unroll
    for (int r = 0; r < RPT; ++r) {
        int row = row0 + ty * RPT + r;
        if (row < n) {
            float s = onrm[row];
            float4 o = make_float4(acc[r].x * s, acc[r].y * s, acc[r].z * s, acc[r].w * s);
            ((float4*)H)[(size_t)row * (FO / 4) + tx] = o;
        }
    }
}

__global__ __launch_bounds__(256) void k_agg128f(const float* __restrict__ h,
                                                 const int* __restrict__ row_ptr,
                                                 const int* __restrict__ eidx,
                                                 const float* __restrict__ inrm,
                                                 const float* __restrict__ bias,
                                                 float* __restrict__ out, int n, int relu) {
    int node = blockIdx.x * 4 + (threadIdx.x >> 6);
    int lane = threadIdx.x & 63;
    if (node >= n) return;
    int beg = row_ptr[node], end = row_ptr[node + 1];
    const float2* h2 = (const float2*)h;
    float ax = 0.f, ay = 0.f;
    for (int j = beg; j < end; ++j) {
        int s = eidx[j];
        float2 v = h2[(size_t)s * 64 + lane];
        ax += v.x;
        ay += v.y;
    }
    float nrm = inrm[node];
    float2 b2 = ((const float2*)bias)[lane];
    float ox = ax * nrm + b2.x;
    float oy = ay * nrm + b2.y;
    if (relu) { ox = fmaxf(ox, 0.f); oy = fmaxf(oy, 0.f); }
    float2 o; o.x = ox; o.y = oy;
    ((float2*)out)[(size_t)node * 64 + lane] = o;
}

__global__ __launch_bounds__(256) void k_agg64f(const float* __restrict__ h,
                                                const int* __restrict__ row_ptr,
                                                const int* __restrict__ eidx,
                                                const float* __restrict__ inrm,
                                                const float* __restrict__ bias,
                                                float* __restrict__ out, int n) {
    int node = blockIdx.x * 4 + (threadIdx.x >> 6);
    int lane = threadIdx.x & 63;
    if (node >= n) return;
    int beg = row_ptr[node], end = row_ptr[node + 1];
    float acc = 0.f;
    for (int j = beg; j < end; ++j) {
        int s = eidx[j];
        acc += h[(size_t)s * 64 + lane];
    }
    out[(size_t)node * 64 + lane] = acc * inrm[node] + bias[lane];
}

// Legacy atomic preprocessing (fallback only)
__global__ void k_degrees_leg(const int* __restrict__ src, const int* __restrict__ dst,
                              int ne, int* __restrict__ degs, int* __restrict__ degd) {
    int i = blockIdx.x * blockDim.x + threadIdx.x;
    if (i < ne) {
        atomicAdd(&degs[src[i]], 1);
        atomicAdd(&degd[dst[i]], 1);
    }
}
__global__ void k_norms_leg(const int* __restrict__ degs, const int* __restrict__ degd,
                            float* __restrict__ onrm, float* __restrict__ inrm,
                            int* __restrict__ degd_sum, int n) {
    int i = blockIdx.x * blockDim.x + threadIdx.x;
    if (i < n) {
        degd_sum[i] = degd[i];
        onrm[i] = rsqrtf((float)max(degs[i], 1));
        inrm[i] = rsqrtf((float)max(degd[i], 1));
    }
}
__global__ void k_copy_int(const int* __restrict__ a, int* __restrict__ b, int n) {
    int i = blockIdx.x * blockDim.x + threadIdx.x;
    if (i < n) b[i] = a[i];
}
__global__ void k_build_csr_leg(const int* __restrict__ src, const int* __restrict__ dst,
                                int ne, int* __restrict__ cursor, int* __restrict__ eidx) {
    int i = blockIdx.x * blockDim.x + threadIdx.x;
    if (i < ne) {
        int p = atomicAdd(&cursor[dst[i]], 1);
        eidx[p] = src[i];
    }
}

static inline size_t align_up(size_t v, size_t a) { return (v + a - 1) & ~(a - 1); }

extern "C" void kernel_launch(void* const* d_in, const int* in_sizes, int n_in,
                              void* d_out, int out_size, void* d_ws, size_t ws_size,
                              hipStream_t stream) {
    const float* x  = (const float*)d_in[0];
    const int* ei   = (const int*)d_in[1];
    const float* W0 = (const float*)d_in[2];
    const float* b0 = (const float*)d_in[3];
    const float* W1 = (const float*)d_in[4];
    const float* b1 = (const float*)d_in[5];
    const float* W2 = (const float*)d_in[6];
    const float* b2 = (const float*)d_in[7];
    const float* W3 = (const float*)d_in[8];
    const float* b3 = (const float*)d_in[9];

    const int n  = in_sizes[0] / 256;   // 50000
    const int ne = in_sizes[1] / 2;     // 800000
    const int n_pad = (n + 127) & ~127;
    const int* src = ei;
    const int* dst = ei + ne;

    const int R = ((n + NRANGE * 64 - 1) / (NRANGE * 64)) * 64;   // 6272 for n=50000
    const int E = (ne + NCHUNK - 1) / NCHUNK;                     // 6250
    const int nscan = NRANGE * R;                                 // 50176
    const bool fast_pre = (R <= RMAX) && (E <= 65535);

    // ---- shared layout ----
    char* ws = (char*)d_ws;
    size_t off = 0;
    auto take = [&](size_t bytes) { void* p = ws + off; off = align_up(off + bytes, 256); return p; };
    int* row_ptr  = (int*)take((size_t)(nscan + 8) * 4);   // indexed to nscan by k_cursors2
    int* degd_sum = (int*)take((size_t)nscan * 4);         // indexed to nscan-1
    int* eidx     = (int*)take((size_t)ne * 4);
    float* onrm   = (float*)take((size_t)n * 4);
    float* inrm   = (float*)take((size_t)n * 4);

    // ---- MFMA-path layout ----
    size_t off_save = off;
    unsigned short* Ah  = (unsigned short*)take((size_t)n_pad * 256 * 2);
    unsigned short* Al  = (unsigned short*)take((size_t)n_pad * 256 * 2);
    __half* hbuf        = (__half*)take((size_t)n * 128 * 2);
    unsigned short* Wh0 = (unsigned short*)take(256 * 128 * 2);
    unsigned short* Wl0 = (unsigned short*)take(256 * 128 * 2);
    unsigned short* Wh1 = (unsigned short*)take(128 * 128 * 2);
    unsigned short* Wl1 = (unsigned short*)take(128 * 128 * 2);
    unsigned short* Wh2 = (unsigned short*)take(128 * 128 * 2);
    unsigned short* Wl2 = (unsigned short*)take(128 * 128 * 2);
    unsigned short* Wh3 = (unsigned short*)take(128 * 64 * 2);
    unsigned short* Wl3 = (unsigned short*)take(128 * 64 * 2);
    bool use_mfma = (off <= ws_size);

    // ---- preprocessing scratch ALIASED onto Ah/Al/hbuf (dead until mm0) ----
    char* pre = (char*)Ah;
    const size_t cntSz = align_up((size_t)NRANGE * NCHUNK * R * 2, 256);
    unsigned short* cnt_s = (unsigned short*)pre;
    unsigned short* cnt_d = (unsigned short*)(pre + cntSz);
    int* cbase            = (int*)(pre + 2 * cntSz);
    unsigned short* pos   = (unsigned short*)(pre + 4 * cntSz);
    int* blocksum         = (int*)(pre + 4 * cntSz + align_up((size_t)ne * 2, 256));

    const int aggGrid = (n + 15) / 16;

    if (fast_pre) {
        // ---- LDS-privatized preprocessing: zero global atomics ----
        const int nblk = nscan / 256;                   // 196 (<=256 required)
        const int wsplitBlocks = use_mfma ? 288 : 0;    // 73728/256
        k_hist<<<NRANGE * NCHUNK + wsplitBlocks, 256, 0, stream>>>(
            src, dst, ne, R, E, cnt_s, cnt_d, pos,
            W0, W1, W2, W3, Wh0, Wl0, Wh1, Wl1, Wh2, Wl2, Wh3, Wl3);
        k_reduce_norms<<<nblk, 256, 0, stream>>>(cnt_s, cnt_d, R, n,
                                                 onrm, inrm, degd_sum, blocksum);
        k_cursors2<<<nblk, 256, 0, stream>>>(blocksum, nblk, degd_sum, cnt_d, R,
                                             row_ptr, cbase, nscan);
        k_csr_scatter<<<(ne + 255) / 256, 256, 0, stream>>>(src, dst, pos, cbase, ne, R, E, eidx);
    } else {
        int* degs   = (int*)pre;
        int* degd   = (int*)pre + n_pad;
        int* cursor = (int*)pre + 2 * n_pad;
        hipMemsetAsync(degs, 0, (size_t)2 * n_pad * 4, stream);
        k_degrees_leg<<<(ne + 255) / 256, 256, 0, stream>>>(src, dst, ne, degs, degd);
        k_norms_leg<<<(n + 255) / 256, 256, 0, stream>>>(degs, degd, onrm, inrm, degd_sum, n);
        k_scan<<<1, 1024, 0, stream>>>(degd_sum, n, row_ptr);
        k_copy_int<<<(n + 255) / 256, 256, 0, stream>>>(row_ptr, cursor, n);
        k_build_csr_leg<<<(ne + 255) / 256, 256, 0, stream>>>(src, dst, ne, cursor, eidx);
        if (use_mfma)
            k_split_w_all<<<(73728 + 255) / 256, 256, 0, stream>>>(
                W0, W1, W2, W3, Wh0, Wl0, Wh1, Wl1, Wh2, Wl2, Wh3, Wl3);
    }

    if (use_mfma) {
        const int mmGrid = n_pad / 128;
        // L0: 256 -> 128, A = x fp32 (split fused, onrm folded)
        k_mm<256, 128, true><<<mmGrid, 256, 0, stream>>>(nullptr, nullptr, x, onrm, Wh0, Wl0, hbuf, n);
        k_agg128_split<<<aggGrid, 256, 0, stream>>>(hbuf, row_ptr, eidx, inrm, onrm, b0, Ah, Al, n);
        // L1
        k_mm<128, 128, false><<<mmGrid, 256, 0, stream>>>(Ah, Al, nullptr, nullptr, Wh1, Wl1, hbuf, n);
        k_agg128_split<<<aggGrid, 256, 0, stream>>>(hbuf, row_ptr, eidx, inrm, onrm, b1, Ah, Al, n);
        // L2
        k_mm<128, 128, false><<<mmGrid, 256, 0, stream>>>(Ah, Al, nullptr, nullptr, Wh2, Wl2, hbuf, n);
        k_agg128_split<<<aggGrid, 256, 0, stream>>>(hbuf, row_ptr, eidx, inrm, onrm, b2, Ah, Al, n);
        // L3: 128 -> 64
        k_mm<128, 64, false><<<mmGrid, 256, 0, stream>>>(Ah, Al, nullptr, nullptr, Wh3, Wl3, hbuf, n);
        k_agg64<<<aggGrid, 256, 0, stream>>>(hbuf, row_ptr, eidx, inrm, b3, (float*)d_out, n);
    } else {
        // fp32 fallback
        off = off_save;
        float* hbufF  = (float*)take((size_t)n * 128 * 4);
        float* xnextF = (float*)take((size_t)n * 128 * 4);
        const int aggGridF = (n + 3) / 4;

        k_matmul<256, 128, 32, 8, 4><<<(n + 31) / 32, dim3(32, 8), 0, stream>>>(x, W0, onrm, hbufF, n);
        k_agg128f<<<aggGridF, 256, 0, stream>>>(hbufF, row_ptr, eidx, inrm, b0, xnextF, n, 1);
        k_matmul<128, 128, 32, 8, 4><<<(n + 31) / 32, dim3(32, 8), 0, stream>>>(xnextF, W1, onrm, hbufF, n);
        k_agg128f<<<aggGridF, 256, 0, stream>>>(hbufF, row_ptr, eidx, inrm, b1, xnextF, n, 1);
        k_matmul<128, 128, 32, 8, 4><<<(n + 31) / 32, dim3(32, 8), 0, stream>>>(xnextF, W2, onrm, hbufF, n);
        k_agg128f<<<aggGridF, 256, 0, stream>>>(hbufF, row_ptr, eidx, inrm, b2, xnextF, n, 1);
        k_matmul<128, 64, 16, 16, 4><<<(n + 63) / 64, dim3(16, 16), 0, stream>>>(xnextF, W3, onrm, hbufF, n);
        k_agg64f<<<aggGridF, 256, 0, stream>>>(hbufF, row_ptr, eidx, inrm, b3, (float*)d_out, n);
    }
}

// Round 7
// 346.483 us; speedup vs baseline: 1.1012x; 1.1012x over previous
//
#include <hip/hip_runtime.h>
#include <hip/hip_fp16.h>

// ---------------------------------------------------------------------------
// GCN 4-layer forward on MI355X (gfx950).
//   Preprocess (ZERO global atomics): LDS range histograms (8 ranges x 128
//     chunks, PACKED 16-bit counters -> 25KB LDS) + per-edge bucket rank ->
//     reduce+norms -> parallel hierarchical scan fused into cursor kernel ->
//     single-pass CSR scatter. Chunk-co-located XCD swizzle for edge L2 reuse.
//     Weight split rides as extra blocks on k_hist's grid.
//   GEMMs: bf16-split MFMA (3-term, ~fp32 precision), B staged in LDS
//     (XOR-swizzled). L0 (FA: A = fp32 x, split fused): BM=128/KT=128 full-N
//     (x read ONCE). L1-L3 (non-FA): COLUMN-SPLIT x2 -> 784 blocks, 32/16KB
//     LDS, full-A register prefetch (measured-good in R4; R4's regression was
//     col-splitting the FA layer, which double-read the 51MB x).
//   h in fp16 -> CSR gather with 16-lane/16B row segments (4 nodes/wave),
//     fused epilogue + bf16 hi/lo split.
// ---------------------------------------------------------------------------

typedef __attribute__((ext_vector_type(8))) short short8;
typedef __attribute__((ext_vector_type(4))) float f32x4;

#define NRANGE 8
#define NCHUNK 128
#define RMAX   6272   // 8*6272 = 50176 >= 50000 nodes; LDS = 2*(6272/2)*4 = 25088 B

__device__ inline unsigned short bf16_rne(float v) {
    union { float f; unsigned u; } c; c.f = v;
    unsigned u = c.u;
    unsigned lsb = (u >> 16) & 1u;
    u += 0x7fffu + lsb;
    return (unsigned short)(u >> 16);
}
__device__ inline float bf16_to_f(unsigned short h) {
    union { unsigned u; float f; } c; c.u = ((unsigned)h) << 16;
    return c.f;
}
__device__ inline void split_bf16(float v, unsigned short& hi, unsigned short& lo) {
    hi = bf16_rne(v);
    lo = bf16_rne(v - bf16_to_f(hi));
}

// ---------------------------------------------------------------------------
// Preprocessing — LDS-privatized histograms, packed 16-bit counters.
// ---------------------------------------------------------------------------

__global__ __launch_bounds__(256) void k_hist(const int* __restrict__ src,
                                              const int* __restrict__ dst,
                                              int ne, int R, int E,
                                              unsigned short* __restrict__ cnt_s,
                                              unsigned short* __restrict__ cnt_d,
                                              unsigned short* __restrict__ pos,
                                              const float* __restrict__ W0,
                                              const float* __restrict__ W1,
                                              const float* __restrict__ W2,
                                              const float* __restrict__ W3,
                                              unsigned short* __restrict__ Wh0, unsigned short* __restrict__ Wl0,
                                              unsigned short* __restrict__ Wh1, unsigned short* __restrict__ Wl1,
                                              unsigned short* __restrict__ Wh2, unsigned short* __restrict__ Wl2,
                                              unsigned short* __restrict__ Wh3, unsigned short* __restrict__ Wl3) {
    __shared__ int hs32[RMAX / 2];
    __shared__ int hd32[RMAX / 2];
    if (blockIdx.x >= NRANGE * NCHUNK) {
        // ---- weight split tail blocks (288 blocks x 256 = 73728 elements) ----
        int i = (blockIdx.x - NRANGE * NCHUNK) * 256 + threadIdx.x;
        const float* W; unsigned short *Wh, *Wl; int K, F, off;
        if (i < 32768)                     { W = W0; Wh = Wh0; Wl = Wl0; K = 256; F = 128; off = i; }
        else if (i < 32768 + 16384)        { W = W1; Wh = Wh1; Wl = Wl1; K = 128; F = 128; off = i - 32768; }
        else if (i < 32768 + 32768)        { W = W2; Wh = Wh2; Wl = Wl2; K = 128; F = 128; off = i - 49152; }
        else if (i < 32768 + 32768 + 8192) { W = W3; Wh = Wh3; Wl = Wl3; K = 128; F = 64;  off = i - 65536; }
        else return;
        int k = off / F, c = off % F;
        unsigned short h, l;
        split_bf16(W[k * F + c], h, l);
        Wh[c * K + k] = h;
        Wl[c * K + k] = l;
        return;
    }
    // chunk-major decode: c = bid % NCHUNK -> XCD = c % 8 (NCHUNK % 8 == 0),
    // so all 8 range-blocks of a chunk share one XCD's L2 for the edge reads.
    int c = blockIdx.x & (NCHUNK - 1);
    int r = blockIdx.x >> 7;
    int tid = threadIdx.x;
    int Rh = R >> 1;
    for (int i = tid; i < Rh; i += 256) { hs32[i] = 0; hd32[i] = 0; }
    __syncthreads();
    int lo = r * R;
    int e0 = c * E, e1 = min(e0 + E, ne);
    for (int i = e0 + tid; i < e1; i += 256) {
        int s = src[i], d = dst[i];
        unsigned ps = (unsigned)(s - lo);
        unsigned pd = (unsigned)(d - lo);
        if (ps < (unsigned)R)
            atomicAdd(&hs32[ps >> 1], 1 << ((ps & 1) << 4));
        if (pd < (unsigned)R) {
            int sh = (pd & 1) << 4;
            int old = atomicAdd(&hd32[pd >> 1], 1 << sh);
            pos[i] = (unsigned short)((old >> sh) & 0xffff);   // rank in bucket
        }
    }
    __syncthreads();
    int base2 = (r * NCHUNK + c) * Rh;
    int* cs32 = (int*)cnt_s;
    int* cd32 = (int*)cnt_d;
    for (int i = tid; i < Rh; i += 256) {
        cs32[base2 + i] = hs32[i];
        cd32[base2 + i] = hd32[i];
    }
}

// Reduce per-node degrees + norms, AND emit per-block (256-node) degree sums
// for the hierarchical scan. Grid must be exactly (NRANGE*R)/256 blocks.
__global__ __launch_bounds__(256) void k_reduce_norms(const unsigned short* __restrict__ cnt_s,
                                                      const unsigned short* __restrict__ cnt_d,
                                                      int R, int n,
                                                      float* __restrict__ onrm,
                                                      float* __restrict__ inrm,
                                                      int* __restrict__ degd_sum,
                                                      int* __restrict__ blocksum) {
    __shared__ int red[256];
    int tid = threadIdx.x;
    int i = blockIdx.x * 256 + tid;
    int r = i / R, ip = i - r * R;
    int ds = 0, dd = 0;
    for (int c = 0; c < NCHUNK; ++c) {
        ds += cnt_s[(r * NCHUNK + c) * R + ip];
        dd += cnt_d[(r * NCHUNK + c) * R + ip];
    }
    degd_sum[i] = dd;
    if (i < n) {
        onrm[i] = rsqrtf((float)max(ds, 1));
        inrm[i] = rsqrtf((float)max(dd, 1));
    }
    // block-wide sum of dd
    red[tid] = dd;
    __syncthreads();
#pragma unroll
    for (int off = 128; off > 0; off >>= 1) {
        if (tid < off) red[tid] += red[tid + off];
        __syncthreads();
    }
    if (tid == 0) blocksum[blockIdx.x] = red[0];
}

// Fused parallel scan + cursor bases.
__global__ __launch_bounds__(256) void k_cursors2(const int* __restrict__ blocksum, int nblk,
                                                  const int* __restrict__ degd_sum,
                                                  const unsigned short* __restrict__ cnt_d, int R,
                                                  int* __restrict__ row_ptr,
                                                  int* __restrict__ cbase, int total_i) {
    __shared__ int bs[256];
    __shared__ int wsum[4];
    int tid = threadIdx.x;
    bs[tid] = (tid < nblk) ? blocksum[tid] : 0;
    __syncthreads();
#pragma unroll
    for (int off = 1; off < 256; off <<= 1) {
        int v = bs[tid];
        int u = (tid >= off) ? bs[tid - off] : 0;
        __syncthreads();
        bs[tid] = v + u;
        __syncthreads();
    }
    int base = (blockIdx.x > 0) ? bs[blockIdx.x - 1] : 0;

    int i = blockIdx.x * 256 + tid;
    int dd = degd_sum[i];
    int lane = tid & 63, wid = tid >> 6;
    int x = dd;
#pragma unroll
    for (int off = 1; off < 64; off <<= 1) {
        int y = __shfl_up(x, off, 64);
        if (lane >= off) x += y;
    }
    if (lane == 63) wsum[wid] = x;
    __syncthreads();
    int wbase = 0;
    for (int wp = 0; wp < wid; ++wp) wbase += wsum[wp];
    int excl = base + wbase + (x - dd);
    row_ptr[i] = excl;
    if (i == total_i - 1) row_ptr[total_i] = excl + dd;

    int r = i / R, ip = i - r * R;
    int run = excl;
    for (int c = 0; c < NCHUNK; ++c) {
        int idx = (r * NCHUNK + c) * R + ip;
        cbase[idx] = run;
        run += cnt_d[idx];
    }
}

__global__ void k_csr_scatter(const int* __restrict__ src,
                              const int* __restrict__ dst,
                              const unsigned short* __restrict__ pos,
                              const int* __restrict__ cbase,
                              int ne, int R, int E,
                              int* __restrict__ eidx) {
    int i = blockIdx.x * blockDim.x + threadIdx.x;
    if (i >= ne) return;
    int d = dst[i];
    int r = d / R, ip = d - r * R;
    int c = i / E;
    eidx[cbase[(r * NCHUNK + c) * R + ip] + pos[i]] = src[i];
}

// ---------------------------------------------------------------------------
// Weight split (standalone — only used on the legacy preprocessing path)
// ---------------------------------------------------------------------------

__global__ void k_split_w_all(const float* __restrict__ W0, const float* __restrict__ W1,
                              const float* __restrict__ W2, const float* __restrict__ W3,
                              unsigned short* __restrict__ Wh0, unsigned short* __restrict__ Wl0,
                              unsigned short* __restrict__ Wh1, unsigned short* __restrict__ Wl1,
                              unsigned short* __restrict__ Wh2, unsigned short* __restrict__ Wl2,
                              unsigned short* __restrict__ Wh3, unsigned short* __restrict__ Wl3) {
    int i = blockIdx.x * blockDim.x + threadIdx.x;
    const float* W; unsigned short *Wh, *Wl; int K, F, off;
    if (i < 32768)                    { W = W0; Wh = Wh0; Wl = Wl0; K = 256; F = 128; off = i; }
    else if (i < 32768 + 16384)       { W = W1; Wh = Wh1; Wl = Wl1; K = 128; F = 128; off = i - 32768; }
    else if (i < 32768 + 32768)       { W = W2; Wh = Wh2; Wl = Wl2; K = 128; F = 128; off = i - 49152; }
    else if (i < 32768 + 32768 + 8192){ W = W3; Wh = Wh3; Wl = Wl3; K = 128; F = 64;  off = i - 65536; }
    else return;
    int k = off / F, c = off % F;
    unsigned short h, l;
    split_bf16(W[k * F + c], h, l);
    Wh[c * K + k] = h;
    Wl[c * K + k] = l;
}

// ---------------------------------------------------------------------------
// MFMA GEMM (full-N, FA layer): BM=128, KT=128, B staged in LDS (XOR-swizzle).
// A read from fp32 X, *onrm + bf16 split fused into fragment load.
// ---------------------------------------------------------------------------
template <int K, int N>
__global__ __launch_bounds__(256) void k_mm_fa(const float* __restrict__ Xf,
                                               const float* __restrict__ onrm,
                                               const unsigned short* __restrict__ Bh,
                                               const unsigned short* __restrict__ Bl,
                                               __half* __restrict__ H, int n) {
    constexpr int KT = 128;
    constexpr int NT = N / 16;
    constexpr int NKT = K / KT;
    __shared__ unsigned short sBh[N * KT];
    __shared__ unsigned short sBl[N * KT];

    int tid = threadIdx.x;
    int w = tid >> 6, lane = tid & 63;
    int quad = lane >> 4, l16 = lane & 15;
    int row_base = blockIdx.x * 128 + w * 32;

    int ar0 = row_base + l16;
    int ar1 = row_base + 16 + l16;
    if (ar0 >= n) ar0 = n - 1;
    if (ar1 >= n) ar1 = n - 1;

    float on0 = onrm[ar0], on1 = onrm[ar1];

    f32x4 acc[2][NT];
#pragma unroll
    for (int m = 0; m < 2; ++m)
#pragma unroll
        for (int t = 0; t < NT; ++t) acc[m][t] = (f32x4){0.f, 0.f, 0.f, 0.f};

    for (int kt = 0; kt < NKT; ++kt) {
        if (kt) __syncthreads();
        for (int idx = tid; idx < N * 16; idx += 256) {
            int c = idx >> 4;
            int g = idx & 15;
            short8 vh = *(const short8*)(Bh + (size_t)c * K + kt * KT + g * 8);
            short8 vl = *(const short8*)(Bl + (size_t)c * K + kt * KT + g * 8);
            int sg = g ^ (c & 15);
            *(short8*)(&sBh[c * KT + sg * 8]) = vh;
            *(short8*)(&sBl[c * KT + sg * 8]) = vl;
        }
        __syncthreads();

#pragma unroll
        for (int k0 = 0; k0 < KT; k0 += 32) {
            int eoff = k0 + quad * 8;
            short8 a0hv, a0lv, a1hv, a1lv;
            {
                const float* x0 = Xf + (size_t)ar0 * K + kt * KT + eoff;
                const float* x1 = Xf + (size_t)ar1 * K + kt * KT + eoff;
                float4 p00 = *(const float4*)x0;
                float4 p01 = *(const float4*)(x0 + 4);
                float4 p10 = *(const float4*)x1;
                float4 p11 = *(const float4*)(x1 + 4);
                float e0[8] = {p00.x, p00.y, p00.z, p00.w, p01.x, p01.y, p01.z, p01.w};
                float e1[8] = {p10.x, p10.y, p10.z, p10.w, p11.x, p11.y, p11.z, p11.w};
#pragma unroll
                for (int q = 0; q < 8; ++q) {
                    unsigned short hh, ll;
                    split_bf16(e0[q] * on0, hh, ll);
                    a0hv[q] = (short)hh; a0lv[q] = (short)ll;
                    split_bf16(e1[q] * on1, hh, ll);
                    a1hv[q] = (short)hh; a1lv[q] = (short)ll;
                }
            }
            int g = (k0 >> 3) + quad;
            int sg8 = (g ^ l16) * 8;
#pragma unroll
            for (int t = 0; t < NT; ++t) {
                int cb = (t * 16 + l16) * KT;
                short8 bh = *(const short8*)(&sBh[cb + sg8]);
                short8 bl = *(const short8*)(&sBl[cb + sg8]);
                acc[0][t] = __builtin_amdgcn_mfma_f32_16x16x32_bf16(a0hv, bh, acc[0][t], 0, 0, 0);
                acc[0][t] = __builtin_amdgcn_mfma_f32_16x16x32_bf16(a0lv, bh, acc[0][t], 0, 0, 0);
                acc[0][t] = __builtin_amdgcn_mfma_f32_16x16x32_bf16(a0hv, bl, acc[0][t], 0, 0, 0);
                acc[1][t] = __builtin_amdgcn_mfma_f32_16x16x32_bf16(a1hv, bh, acc[1][t], 0, 0, 0);
                acc[1][t] = __builtin_amdgcn_mfma_f32_16x16x32_bf16(a1lv, bh, acc[1][t], 0, 0, 0);
                acc[1][t] = __builtin_amdgcn_mfma_f32_16x16x32_bf16(a1hv, bl, acc[1][t], 0, 0, 0);
            }
        }
    }

#pragma unroll
    for (int m = 0; m < 2; ++m) {
#pragma unroll
        for (int t = 0; t < NT; ++t) {
#pragma unroll
            for (int r = 0; r < 4; ++r) {
                int grow = row_base + m * 16 + quad * 4 + r;
                if (grow < n) H[(size_t)grow * N + t * 16 + l16] = __float2half(acc[m][t][r]);
            }
        }
    }
}

// ---------------------------------------------------------------------------
// MFMA GEMM (column-split, non-FA layers): BM=128, KT=128, NC cols per block.
// Grid = rows/128 * N/NC (784): 2x the waves of full-N; LDS = NC*KT*2*2 B.
// Wave's whole A panel (16 short8) prefetched to registers at entry ->
// reg-resident MFMA loop. Per-acc MFMA k-order bit-identical to full-N.
// ---------------------------------------------------------------------------
template <int K, int N, int NC>
__global__ __launch_bounds__(256) void k_mm_cs(const unsigned short* __restrict__ Ah,
                                               const unsigned short* __restrict__ Al,
                                               const unsigned short* __restrict__ Bh,
                                               const unsigned short* __restrict__ Bl,
                                               __half* __restrict__ H, int n) {
    constexpr int KT = 128;
    constexpr int NT = NC / 16;
    constexpr int NKT = K / KT;
    constexpr int CS = N / NC;
    constexpr int NPH = K / 32;
    __shared__ unsigned short sBh[NC * KT];
    __shared__ unsigned short sBl[NC * KT];

    int tid = threadIdx.x;
    int w = tid >> 6, lane = tid & 63;
    int quad = lane >> 4, l16 = lane & 15;
    int cblk = blockIdx.x % CS;          // low bits: column part (co-dispatch)
    int rblk = blockIdx.x / CS;
    int row_base = rblk * 128 + w * 32;
    int col0 = cblk * NC;

    int ar0 = row_base + l16;
    int ar1 = row_base + 16 + l16;
    if (ar0 >= n) ar0 = n - 1;
    if (ar1 >= n) ar1 = n - 1;

    // ---- full-A register prefetch: 4*NPH independent 16B loads ----
    short8 pa0h[NPH], pa0l[NPH], pa1h[NPH], pa1l[NPH];
#pragma unroll
    for (int ph = 0; ph < NPH; ++ph) {
        int eoff = ph * 32 + quad * 8;
        pa0h[ph] = *(const short8*)(Ah + (size_t)ar0 * K + eoff);
        pa0l[ph] = *(const short8*)(Al + (size_t)ar0 * K + eoff);
        pa1h[ph] = *(const short8*)(Ah + (size_t)ar1 * K + eoff);
        pa1l[ph] = *(const short8*)(Al + (size_t)ar1 * K + eoff);
    }

    f32x4 acc[2][NT];
#pragma unroll
    for (int m = 0; m < 2; ++m)
#pragma unroll
        for (int t = 0; t < NT; ++t) acc[m][t] = (f32x4){0.f, 0.f, 0.f, 0.f};

    for (int kt = 0; kt < NKT; ++kt) {
        if (kt) __syncthreads();
        // stage B k-slice for cols [col0, col0+NC)
        for (int idx = tid; idx < NC * 16; idx += 256) {
            int c = idx >> 4;
            int g = idx & 15;
            short8 vh = *(const short8*)(Bh + (size_t)(col0 + c) * K + kt * KT + g * 8);
            short8 vl = *(const short8*)(Bl + (size_t)(col0 + c) * K + kt * KT + g * 8);
            int sg = g ^ (c & 15);
            *(short8*)(&sBh[c * KT + sg * 8]) = vh;
            *(short8*)(&sBl[c * KT + sg * 8]) = vl;
        }
        __syncthreads();

#pragma unroll
        for (int k0 = 0; k0 < KT; k0 += 32) {
            constexpr int PH_MASK = NPH - 1;
            int ph = ((kt * KT + k0) >> 5) & PH_MASK;   // static after unroll
            short8 a0hv = pa0h[ph], a0lv = pa0l[ph];
            short8 a1hv = pa1h[ph], a1lv = pa1l[ph];
            int g = (k0 >> 3) + quad;
#pragma unroll
            for (int t = 0; t < NT; ++t) {
                int cl = t * 16 + l16;
                int cb = cl * KT;
                int sg8 = (g ^ (cl & 15)) * 8;
                short8 bh = *(const short8*)(&sBh[cb + sg8]);
                short8 bl = *(const short8*)(&sBl[cb + sg8]);
                acc[0][t] = __builtin_amdgcn_mfma_f32_16x16x32_bf16(a0hv, bh, acc[0][t], 0, 0, 0);
                acc[0][t] = __builtin_amdgcn_mfma_f32_16x16x32_bf16(a0lv, bh, acc[0][t], 0, 0, 0);
                acc[0][t] = __builtin_amdgcn_mfma_f32_16x16x32_bf16(a0hv, bl, acc[0][t], 0, 0, 0);
                acc[1][t] = __builtin_amdgcn_mfma_f32_16x16x32_bf16(a1hv, bh, acc[1][t], 0, 0, 0);
                acc[1][t] = __builtin_amdgcn_mfma_f32_16x16x32_bf16(a1lv, bh, acc[1][t], 0, 0, 0);
                acc[1][t] = __builtin_amdgcn_mfma_f32_16x16x32_bf16(a1hv, bl, acc[1][t], 0, 0, 0);
            }
        }
    }

#pragma unroll
    for (int m = 0; m < 2; ++m) {
#pragma unroll
        for (int t = 0; t < NT; ++t) {
#pragma unroll
            for (int r = 0; r < 4; ++r) {
                int grow = row_base + m * 16 + quad * 4 + r;
                if (grow < n) H[(size_t)grow * N + col0 + t * 16 + l16] = __float2half(acc[m][t][r]);
            }
        }
    }
}

// ---------------------------------------------------------------------------
// Aggregation: 16-lane row segments, 4 nodes/wave (best-measured R2 config).
// ---------------------------------------------------------------------------

__global__ __launch_bounds__(256) void k_agg128_split(const __half* __restrict__ h,
                                                      const int* __restrict__ row_ptr,
                                                      const int* __restrict__ eidx,
                                                      const float* __restrict__ inrm,
                                                      const float* __restrict__ onrm,
                                                      const float* __restrict__ bias,
                                                      unsigned short* __restrict__ Ah,
                                                      unsigned short* __restrict__ Al, int n) {
    int wave = threadIdx.x >> 6;
    int lane = threadIdx.x & 63;
    int g = lane >> 4;
    int l = lane & 15;
    int node = blockIdx.x * 16 + wave * 4 + g;
    bool valid = node < n;
    int nd = valid ? node : n - 1;
    int beg = row_ptr[nd], end = row_ptr[nd + 1];
    const short8* h8 = (const short8*)h;   // row = 16 granules of 16B

    float a[4][8];
#pragma unroll
    for (int u = 0; u < 4; ++u)
#pragma unroll
        for (int c = 0; c < 8; ++c) a[u][c] = 0.f;

    int j = beg;
    for (; j + 4 <= end; j += 4) {
        int s[4];
#pragma unroll
        for (int u = 0; u < 4; ++u) s[u] = eidx[j + u];
        short8 v[4];
#pragma unroll
        for (int u = 0; u < 4; ++u) v[u] = h8[(size_t)s[u] * 16 + l];
#pragma unroll
        for (int u = 0; u < 4; ++u) {
            const __half2* ph = reinterpret_cast<const __half2*>(&v[u]);
#pragma unroll
            for (int p = 0; p < 4; ++p) {
                float2 f = __half22float2(ph[p]);
                a[u][2 * p] += f.x;
                a[u][2 * p + 1] += f.y;
            }
        }
    }
    for (; j < end; ++j) {
        short8 v = h8[(size_t)eidx[j] * 16 + l];
        const __half2* ph = reinterpret_cast<const __half2*>(&v);
#pragma unroll
        for (int p = 0; p < 4; ++p) {
            float2 f = __half22float2(ph[p]);
            a[0][2 * p] += f.x;
            a[0][2 * p + 1] += f.y;
        }
    }

    float nrm = inrm[nd];
    float on = onrm[nd];
    float4 b0 = ((const float4*)bias)[l * 2];
    float4 b1 = ((const float4*)bias)[l * 2 + 1];
    float bb[8] = {b0.x, b0.y, b0.z, b0.w, b1.x, b1.y, b1.z, b1.w};
    short8 hv, lv;
#pragma unroll
    for (int c = 0; c < 8; ++c) {
        float s = (a[0][c] + a[1][c]) + (a[2][c] + a[3][c]);
        float o = fmaxf(s * nrm + bb[c], 0.f) * on;
        unsigned short hh, ll;
        split_bf16(o, hh, ll);
        hv[c] = (short)hh;
        lv[c] = (short)ll;
    }
    if (valid) {
        ((short8*)Ah)[(size_t)node * 16 + l] = hv;
        ((short8*)Al)[(size_t)node * 16 + l] = lv;
    }
}

// FO=64 final layer: 16-lane x 8B segments (4 nodes/wave), unroll 8, fp32 out.
__global__ __launch_bounds__(256) void k_agg64(const __half* __restrict__ h,
                                               const int* __restrict__ row_ptr,
                                               const int* __restrict__ eidx,
                                               const float* __restrict__ inrm,
                                               const float* __restrict__ bias,
                                               float* __restrict__ out, int n) {
    int wave = threadIdx.x >> 6;
    int lane = threadIdx.x & 63;
    int g = lane >> 4;
    int l = lane & 15;
    int node = blockIdx.x * 16 + wave * 4 + g;
    bool valid = node < n;
    int nd = valid ? node : n - 1;
    int beg = row_ptr[nd], end = row_ptr[nd + 1];
    const ushort4* h4 = (const ushort4*)h;  // row = 16 granules of 8B

    float a[8][4];
#pragma unroll
    for (int u = 0; u < 8; ++u)
#pragma unroll
        for (int c = 0; c < 4; ++c) a[u][c] = 0.f;

    int j = beg;
    for (; j + 8 <= end; j += 8) {
        int s[8];
#pragma unroll
        for (int u = 0; u < 8; ++u) s[u] = eidx[j + u];
        ushort4 v[8];
#pragma unroll
        for (int u = 0; u < 8; ++u) v[u] = h4[(size_t)s[u] * 16 + l];
#pragma unroll
        for (int u = 0; u < 8; ++u) {
            const __half2* ph = reinterpret_cast<const __half2*>(&v[u]);
            float2 f0 = __half22float2(ph[0]);
            float2 f1 = __half22float2(ph[1]);
            a[u][0] += f0.x; a[u][1] += f0.y; a[u][2] += f1.x; a[u][3] += f1.y;
        }
    }
    for (; j < end; ++j) {
        ushort4 v = h4[(size_t)eidx[j] * 16 + l];
        const __half2* ph = reinterpret_cast<const __half2*>(&v);
        float2 f0 = __half22float2(ph[0]);
        float2 f1 = __half22float2(ph[1]);
        a[0][0] += f0.x; a[0][1] += f0.y; a[0][2] += f1.x; a[0][3] += f1.y;
    }

    float nrm = inrm[nd];
    float4 b4 = ((const float4*)bias)[l];
    float4 o;
    float s0 = ((a[0][0] + a[1][0]) + (a[2][0] + a[3][0])) + ((a[4][0] + a[5][0]) + (a[6][0] + a[7][0]));
    float s1 = ((a[0][1] + a[1][1]) + (a[2][1] + a[3][1])) + ((a[4][1] + a[5][1]) + (a[6][1] + a[7][1]));
    float s2 = ((a[0][2] + a[1][2]) + (a[2][2] + a[3][2])) + ((a[4][2] + a[5][2]) + (a[6][2] + a[7][2]));
    float s3 = ((a[0][3] + a[1][3]) + (a[2][3] + a[3][3])) + ((a[4][3] + a[5][3]) + (a[6][3] + a[7][3]));
    o.x = s0 * nrm + b4.x;
    o.y = s1 * nrm + b4.y;
    o.z = s2 * nrm + b4.z;
    o.w = s3 * nrm + b4.w;
    if (valid) ((float4*)out)[(size_t)node * 16 + l] = o;
}

// ---------------------------------------------------------------------------
// Legacy single-block scan (only for fallback path)
// ---------------------------------------------------------------------------
__global__ __launch_bounds__(1024) void k_scan(const int* __restrict__ deg, int n,
                                               int* __restrict__ row_ptr) {
    __shared__ int wsum[16];
    __shared__ int carry;
    int tid = threadIdx.x;
    int lane = tid & 63;
    int wid = tid >> 6;
    if (tid == 0) carry = 0;
    __syncthreads();
    int n4 = (n + 3) >> 2;
    for (int base = 0; base < n4; base += 1024) {
        int i4 = base + tid;
        int4 v = make_int4(0, 0, 0, 0);
        if (i4 < n4) v = ((const int4*)deg)[i4];
        int s = v.x + v.y + v.z + v.w;
        int x = s;
#pragma unroll
        for (int off = 1; off < 64; off <<= 1) {
            int y = __shfl_up(x, off, 64);
            if (lane >= off) x += y;
        }
        if (lane == 63) wsum[wid] = x;
        __syncthreads();
        if (wid == 0 && lane < 16) {
            int w = wsum[lane];
#pragma unroll
            for (int off = 1; off < 16; off <<= 1) {
                int y = __shfl_up(w, off, 16);
                if (lane >= off) w += y;
            }
            wsum[lane] = w;
        }
        __syncthreads();
        int excl = x - s + carry + (wid > 0 ? wsum[wid - 1] : 0);
        if (i4 < n4) {
            int e0 = excl, e1 = e0 + v.x, e2 = e1 + v.y, e3 = e2 + v.z;
            ((int4*)row_ptr)[i4] = make_int4(e0, e1, e2, e3);
        }
        __syncthreads();
        if (tid == 0) carry += wsum[15];
        __syncthreads();
    }
    if (tid == 0) row_ptr[n] = carry;
}

// ---------------------------------------------------------------------------
// Fallback fp32 path (known-good) — used if workspace too small for MFMA path.
// ---------------------------------------------------------------------------
template <int K, int FO, int TX, int TY, int RPT>
__global__ __launch_bounds__(256) void k_matmul(const float* __restrict__ X,
                                                const float* __restrict__ W,
                                                const float* __restrict__ onrm,
                                                float* __restrict__ H, int n) {
    constexpr int BROWS = TY * RPT;
    constexpr int LDK = K + 1;
    __shared__ float xs[BROWS * LDK];
    int tx = threadIdx.x, ty = threadIdx.y;
    int tid = ty * TX + tx;
    int row0 = blockIdx.x * BROWS;

    for (int idx = tid; idx < BROWS * K; idx += 256) {
        int r = idx / K;
        int k = idx - r * K;
        int row = row0 + r;
        xs[r * LDK + k] = (row < n) ? X[(size_t)row * K + k] : 0.f;
    }
    __syncthreads();

    float4 acc[RPT];
#pragma unroll
    for (int r = 0; r < RPT; ++r) acc[r] = make_float4(0.f, 0.f, 0.f, 0.f);

    const float4* W4 = (const float4*)W;
#pragma unroll 4
    for (int k = 0; k < K; ++k) {
        float4 w = W4[k * (FO / 4) + tx];
#pragma unroll
        for (int r = 0; r < RPT; ++r) {
            float xv = xs[(ty * RPT + r) * LDK + k];
            acc[r].x += xv * w.x;
            acc[r].y += xv * w.y;
            acc[r].z += xv * w.z;
            acc[r].w += xv * w.w;
        }
    }

#pragma unroll
    for (int r = 0; r < RPT; ++r) {
        int row = row0 + ty * RPT + r;
        if (row < n) {
            float s = onrm[row];
            float4 o = make_float4(acc[r].x * s, acc[r].y * s, acc[r].z * s, acc[r].w * s);
            ((float4*)H)[(size_t)row * (FO / 4) + tx] = o;
        }
    }
}

__global__ __launch_bounds__(256) void k_agg128f(const float* __restrict__ h,
                                                 const int* __restrict__ row_ptr,
                                                 const int* __restrict__ eidx,
                                                 const float* __restrict__ inrm,
                                                 const float* __restrict__ bias,
                                                 float* __restrict__ out, int n, int relu) {
    int node = blockIdx.x * 4 + (threadIdx.x >> 6);
    int lane = threadIdx.x & 63;
    if (node >= n) return;
    int beg = row_ptr[node], end = row_ptr[node + 1];
    const float2* h2 = (const float2*)h;
    float ax = 0.f, ay = 0.f;
    for (int j = beg; j < end; ++j) {
        int s = eidx[j];
        float2 v = h2[(size_t)s * 64 + lane];
        ax += v.x;
        ay += v.y;
    }
    float nrm = inrm[node];
    float2 b2 = ((const float2*)bias)[lane];
    float ox = ax * nrm + b2.x;
    float oy = ay * nrm + b2.y;
    if (relu) { ox = fmaxf(ox, 0.f); oy = fmaxf(oy, 0.f); }
    float2 o; o.x = ox; o.y = oy;
    ((float2*)out)[(size_t)node * 64 + lane] = o;
}

__global__ __launch_bounds__(256) void k_agg64f(const float* __restrict__ h,
                                                const int* __restrict__ row_ptr,
                                                const int* __restrict__ eidx,
                                                const float* __restrict__ inrm,
                                                const float* __restrict__ bias,
                                                float* __restrict__ out, int n) {
    int node = blockIdx.x * 4 + (threadIdx.x >> 6);
    int lane = threadIdx.x & 63;
    if (node >= n) return;
    int beg = row_ptr[node], end = row_ptr[node + 1];
    float acc = 0.f;
    for (int j = beg; j < end; ++j) {
        int s = eidx[j];
        acc += h[(size_t)s * 64 + lane];
    }
    out[(size_t)node * 64 + lane] = acc * inrm[node] + bias[lane];
}

// Legacy atomic preprocessing (fallback only)
__global__ void k_degrees_leg(const int* __restrict__ src, const int* __restrict__ dst,
                              int ne, int* __restrict__ degs, int* __restrict__ degd) {
    int i = blockIdx.x * blockDim.x + threadIdx.x;
    if (i < ne) {
        atomicAdd(&degs[src[i]], 1);
        atomicAdd(&degd[dst[i]], 1);
    }
}
__global__ void k_norms_leg(const int* __restrict__ degs, const int* __restrict__ degd,
                            float* __restrict__ onrm, float* __restrict__ inrm,
                            int* __restrict__ degd_sum, int n) {
    int i = blockIdx.x * blockDim.x + threadIdx.x;
    if (i < n) {
        degd_sum[i] = degd[i];
        onrm[i] = rsqrtf((float)max(degs[i], 1));
        inrm[i] = rsqrtf((float)max(degd[i], 1));
    }
}
__global__ void k_copy_int(const int* __restrict__ a, int* __restrict__ b, int n) {
    int i = blockIdx.x * blockDim.x + threadIdx.x;
    if (i < n) b[i] = a[i];
}
__global__ void k_build_csr_leg(const int* __restrict__ src, const int* __restrict__ dst,
                                int ne, int* __restrict__ cursor, int* __restrict__ eidx) {
    int i = blockIdx.x * blockDim.x + threadIdx.x;
    if (i < ne) {
        int p = atomicAdd(&cursor[dst[i]], 1);
        eidx[p] = src[i];
    }
}

static inline size_t align_up(size_t v, size_t a) { return (v + a - 1) & ~(a - 1); }

extern "C" void kernel_launch(void* const* d_in, const int* in_sizes, int n_in,
                              void* d_out, int out_size, void* d_ws, size_t ws_size,
                              hipStream_t stream) {
    const float* x  = (const float*)d_in[0];
    const int* ei   = (const int*)d_in[1];
    const float* W0 = (const float*)d_in[2];
    const float* b0 = (const float*)d_in[3];
    const float* W1 = (const float*)d_in[4];
    const float* b1 = (const float*)d_in[5];
    const float* W2 = (const float*)d_in[6];
    const float* b2 = (const float*)d_in[7];
    const float* W3 = (const float*)d_in[8];
    const float* b3 = (const float*)d_in[9];

    const int n  = in_sizes[0] / 256;   // 50000
    const int ne = in_sizes[1] / 2;     // 800000
    const int n_pad = (n + 127) & ~127;
    const int* src = ei;
    const int* dst = ei + ne;

    const int R = ((n + NRANGE * 64 - 1) / (NRANGE * 64)) * 64;   // 6272 for n=50000
    const int E = (ne + NCHUNK - 1) / NCHUNK;                     // 6250
    const int nscan = NRANGE * R;                                 // 50176
    const bool fast_pre = (R <= RMAX) && (E <= 65535);

    // ---- shared layout ----
    char* ws = (char*)d_ws;
    size_t off = 0;
    auto take = [&](size_t bytes) { void* p = ws + off; off = align_up(off + bytes, 256); return p; };
    int* row_ptr  = (int*)take((size_t)(nscan + 8) * 4);   // indexed to nscan by k_cursors2
    int* degd_sum = (int*)take((size_t)nscan * 4);         // indexed to nscan-1
    int* eidx     = (int*)take((size_t)ne * 4);
    float* onrm   = (float*)take((size_t)n * 4);
    float* inrm   = (float*)take((size_t)n * 4);

    // ---- MFMA-path layout ----
    size_t off_save = off;
    unsigned short* Ah  = (unsigned short*)take((size_t)n_pad * 256 * 2);
    unsigned short* Al  = (unsigned short*)take((size_t)n_pad * 256 * 2);
    __half* hbuf        = (__half*)take((size_t)n * 128 * 2);
    unsigned short* Wh0 = (unsigned short*)take(256 * 128 * 2);
    unsigned short* Wl0 = (unsigned short*)take(256 * 128 * 2);
    unsigned short* Wh1 = (unsigned short*)take(128 * 128 * 2);
    unsigned short* Wl1 = (unsigned short*)take(128 * 128 * 2);
    unsigned short* Wh2 = (unsigned short*)take(128 * 128 * 2);
    unsigned short* Wl2 = (unsigned short*)take(128 * 128 * 2);
    unsigned short* Wh3 = (unsigned short*)take(128 * 64 * 2);
    unsigned short* Wl3 = (unsigned short*)take(128 * 64 * 2);
    bool use_mfma = (off <= ws_size);

    // ---- preprocessing scratch ALIASED onto Ah/Al/hbuf (dead until mm0) ----
    char* pre = (char*)Ah;
    const size_t cntSz = align_up((size_t)NRANGE * NCHUNK * R * 2, 256);
    unsigned short* cnt_s = (unsigned short*)pre;
    unsigned short* cnt_d = (unsigned short*)(pre + cntSz);
    int* cbase            = (int*)(pre + 2 * cntSz);
    unsigned short* pos   = (unsigned short*)(pre + 4 * cntSz);
    int* blocksum         = (int*)(pre + 4 * cntSz + align_up((size_t)ne * 2, 256));

    const int aggGrid = (n + 15) / 16;

    if (fast_pre) {
        // ---- LDS-privatized preprocessing: zero global atomics ----
        const int nblk = nscan / 256;                   // 196 (<=256 required)
        const int wsplitBlocks = use_mfma ? 288 : 0;    // 73728/256
        k_hist<<<NRANGE * NCHUNK + wsplitBlocks, 256, 0, stream>>>(
            src, dst, ne, R, E, cnt_s, cnt_d, pos,
            W0, W1, W2, W3, Wh0, Wl0, Wh1, Wl1, Wh2, Wl2, Wh3, Wl3);
        k_reduce_norms<<<nblk, 256, 0, stream>>>(cnt_s, cnt_d, R, n,
                                                 onrm, inrm, degd_sum, blocksum);
        k_cursors2<<<nblk, 256, 0, stream>>>(blocksum, nblk, degd_sum, cnt_d, R,
                                             row_ptr, cbase, nscan);
        k_csr_scatter<<<(ne + 255) / 256, 256, 0, stream>>>(src, dst, pos, cbase, ne, R, E, eidx);
    } else {
        int* degs   = (int*)pre;
        int* degd   = (int*)pre + n_pad;
        int* cursor = (int*)pre + 2 * n_pad;
        hipMemsetAsync(degs, 0, (size_t)2 * n_pad * 4, stream);
        k_degrees_leg<<<(ne + 255) / 256, 256, 0, stream>>>(src, dst, ne, degs, degd);
        k_norms_leg<<<(n + 255) / 256, 256, 0, stream>>>(degs, degd, onrm, inrm, degd_sum, n);
        k_scan<<<1, 1024, 0, stream>>>(degd_sum, n, row_ptr);
        k_copy_int<<<(n + 255) / 256, 256, 0, stream>>>(row_ptr, cursor, n);
        k_build_csr_leg<<<(ne + 255) / 256, 256, 0, stream>>>(src, dst, ne, cursor, eidx);
        if (use_mfma)
            k_split_w_all<<<(73728 + 255) / 256, 256, 0, stream>>>(
                W0, W1, W2, W3, Wh0, Wl0, Wh1, Wl1, Wh2, Wl2, Wh3, Wl3);
    }

    if (use_mfma) {
        const int mmGridFull = n_pad / 128;        // 392 (L0: x read once)
        const int mmGridCS   = (n_pad / 128) * 2;  // 784 (non-FA col-split)
        // L0: 256 -> 128, A = x fp32 (split fused, onrm folded), full-N
        k_mm_fa<256, 128><<<mmGridFull, 256, 0, stream>>>(x, onrm, Wh0, Wl0, hbuf, n);
        k_agg128_split<<<aggGrid, 256, 0, stream>>>(hbuf, row_ptr, eidx, inrm, onrm, b0, Ah, Al, n);
        // L1
        k_mm_cs<128, 128, 64><<<mmGridCS, 256, 0, stream>>>(Ah, Al, Wh1, Wl1, hbuf, n);
        k_agg128_split<<<aggGrid, 256, 0, stream>>>(hbuf, row_ptr, eidx, inrm, onrm, b1, Ah, Al, n);
        // L2
        k_mm_cs<128, 128, 64><<<mmGridCS, 256, 0, stream>>>(Ah, Al, Wh2, Wl2, hbuf, n);
        k_agg128_split<<<aggGrid, 256, 0, stream>>>(hbuf, row_ptr, eidx, inrm, onrm, b2, Ah, Al, n);
        // L3: 128 -> 64
        k_mm_cs<128, 64, 32><<<mmGridCS, 256, 0, stream>>>(Ah, Al, Wh3, Wl3, hbuf, n);
        k_agg64<<<aggGrid, 256, 0, stream>>>(hbuf, row_ptr, eidx, inrm, b3, (float*)d_out, n);
    } else {
        // fp32 fallback
        off = off_save;
        float* hbufF  = (float*)take((size_t)n * 128 * 4);
        float* xnextF = (float*)take((size_t)n * 128 * 4);
        const int aggGridF = (n + 3) / 4;

        k_matmul<256, 128, 32, 8, 4><<<(n + 31) / 32, dim3(32, 8), 0, stream>>>(x, W0, onrm, hbufF, n);
        k_agg128f<<<aggGridF, 256, 0, stream>>>(hbufF, row_ptr, eidx, inrm, b0, xnextF, n, 1);
        k_matmul<128, 128, 32, 8, 4><<<(n + 31) / 32, dim3(32, 8), 0, stream>>>(xnextF, W1, onrm, hbufF, n);
        k_agg128f<<<aggGridF, 256, 0, stream>>>(hbufF, row_ptr, eidx, inrm, b1, xnextF, n, 1);
        k_matmul<128, 128, 32, 8, 4><<<(n + 31) / 32, dim3(32, 8), 0, stream>>>(xnextF, W2, onrm, hbufF, n);
        k_agg128f<<<aggGridF, 256, 0, stream>>>(hbufF, row_ptr, eidx, inrm, b2, xnextF, n, 1);
        k_matmul<128, 64, 16, 16, 4><<<(n + 63) / 64, dim3(16, 16), 0, stream>>>(xnextF, W3, onrm, hbufF, n);
        k_agg64f<<<aggGridF, 256, 0, stream>>>(hbufF, row_ptr, eidx, inrm, b3, (float*)d_out, n);
    }
}

// Round 8
// 337.086 us; speedup vs baseline: 1.1319x; 1.0279x over previous
//
#include <hip/hip_runtime.h>
#include <hip/hip_fp16.h>

// ---------------------------------------------------------------------------
// GCN 4-layer forward on MI355X (gfx950).
//   Preprocess (ZERO global atomics): LDS range histograms (8 ranges x 128
//     chunks, PACKED 16-bit counters -> 25KB LDS) + per-edge bucket rank ->
//     reduce+norms -> parallel hierarchical scan fused into cursor kernel ->
//     single-pass CSR scatter. Chunk-co-located XCD swizzle for edge L2 reuse.
//     Weight split rides as extra blocks on k_hist's grid.
//   GEMMs: bf16-split MFMA (3-term, ~fp32 precision), BM=128/KT=128/full-N
//     (R2 tiling — no traffic inflation), with PER-KT WHOLE-PANEL A REGISTER
//     PREFETCH: all 16 A-loads issued back-to-back before the staging barrier
//     so one HBM round trip covers them (MLP batching; mm was measured
//     ~950 GB/s = in-flight-bytes-starved, not occupancy/barrier-bound).
//   h in fp16 -> CSR gather with 16-lane/16B row segments (4 nodes/wave),
//     fused epilogue + bf16 hi/lo split.
// ---------------------------------------------------------------------------

typedef __attribute__((ext_vector_type(8))) short short8;
typedef __attribute__((ext_vector_type(4))) float f32x4;

#define NRANGE 8
#define NCHUNK 128
#define RMAX   6272   // 8*6272 = 50176 >= 50000 nodes; LDS = 2*(6272/2)*4 = 25088 B

__device__ inline unsigned short bf16_rne(float v) {
    union { float f; unsigned u; } c; c.f = v;
    unsigned u = c.u;
    unsigned lsb = (u >> 16) & 1u;
    u += 0x7fffu + lsb;
    return (unsigned short)(u >> 16);
}
__device__ inline float bf16_to_f(unsigned short h) {
    union { unsigned u; float f; } c; c.u = ((unsigned)h) << 16;
    return c.f;
}
__device__ inline void split_bf16(float v, unsigned short& hi, unsigned short& lo) {
    hi = bf16_rne(v);
    lo = bf16_rne(v - bf16_to_f(hi));
}

// ---------------------------------------------------------------------------
// Preprocessing — LDS-privatized histograms, packed 16-bit counters.
// ---------------------------------------------------------------------------

__global__ __launch_bounds__(256) void k_hist(const int* __restrict__ src,
                                              const int* __restrict__ dst,
                                              int ne, int R, int E,
                                              unsigned short* __restrict__ cnt_s,
                                              unsigned short* __restrict__ cnt_d,
                                              unsigned short* __restrict__ pos,
                                              const float* __restrict__ W0,
                                              const float* __restrict__ W1,
                                              const float* __restrict__ W2,
                                              const float* __restrict__ W3,
                                              unsigned short* __restrict__ Wh0, unsigned short* __restrict__ Wl0,
                                              unsigned short* __restrict__ Wh1, unsigned short* __restrict__ Wl1,
                                              unsigned short* __restrict__ Wh2, unsigned short* __restrict__ Wl2,
                                              unsigned short* __restrict__ Wh3, unsigned short* __restrict__ Wl3) {
    __shared__ int hs32[RMAX / 2];
    __shared__ int hd32[RMAX / 2];
    if (blockIdx.x >= NRANGE * NCHUNK) {
        // ---- weight split tail blocks (288 blocks x 256 = 73728 elements) ----
        int i = (blockIdx.x - NRANGE * NCHUNK) * 256 + threadIdx.x;
        const float* W; unsigned short *Wh, *Wl; int K, F, off;
        if (i < 32768)                     { W = W0; Wh = Wh0; Wl = Wl0; K = 256; F = 128; off = i; }
        else if (i < 32768 + 16384)        { W = W1; Wh = Wh1; Wl = Wl1; K = 128; F = 128; off = i - 32768; }
        else if (i < 32768 + 32768)        { W = W2; Wh = Wh2; Wl = Wl2; K = 128; F = 128; off = i - 49152; }
        else if (i < 32768 + 32768 + 8192) { W = W3; Wh = Wh3; Wl = Wl3; K = 128; F = 64;  off = i - 65536; }
        else return;
        int k = off / F, c = off % F;
        unsigned short h, l;
        split_bf16(W[k * F + c], h, l);
        Wh[c * K + k] = h;
        Wl[c * K + k] = l;
        return;
    }
    // chunk-major decode: c = bid % NCHUNK -> XCD = c % 8 (NCHUNK % 8 == 0),
    // so all 8 range-blocks of a chunk share one XCD's L2 for the edge reads.
    int c = blockIdx.x & (NCHUNK - 1);
    int r = blockIdx.x >> 7;
    int tid = threadIdx.x;
    int Rh = R >> 1;
    for (int i = tid; i < Rh; i += 256) { hs32[i] = 0; hd32[i] = 0; }
    __syncthreads();
    int lo = r * R;
    int e0 = c * E, e1 = min(e0 + E, ne);
    for (int i = e0 + tid; i < e1; i += 256) {
        int s = src[i], d = dst[i];
        unsigned ps = (unsigned)(s - lo);
        unsigned pd = (unsigned)(d - lo);
        if (ps < (unsigned)R)
            atomicAdd(&hs32[ps >> 1], 1 << ((ps & 1) << 4));
        if (pd < (unsigned)R) {
            int sh = (pd & 1) << 4;
            int old = atomicAdd(&hd32[pd >> 1], 1 << sh);
            pos[i] = (unsigned short)((old >> sh) & 0xffff);   // rank in bucket
        }
    }
    __syncthreads();
    int base2 = (r * NCHUNK + c) * Rh;
    int* cs32 = (int*)cnt_s;
    int* cd32 = (int*)cnt_d;
    for (int i = tid; i < Rh; i += 256) {
        cs32[base2 + i] = hs32[i];
        cd32[base2 + i] = hd32[i];
    }
}

// Reduce per-node degrees + norms, AND emit per-block (256-node) degree sums
// for the hierarchical scan. Grid must be exactly (NRANGE*R)/256 blocks.
__global__ __launch_bounds__(256) void k_reduce_norms(const unsigned short* __restrict__ cnt_s,
                                                      const unsigned short* __restrict__ cnt_d,
                                                      int R, int n,
                                                      float* __restrict__ onrm,
                                                      float* __restrict__ inrm,
                                                      int* __restrict__ degd_sum,
                                                      int* __restrict__ blocksum) {
    __shared__ int red[256];
    int tid = threadIdx.x;
    int i = blockIdx.x * 256 + tid;
    int r = i / R, ip = i - r * R;
    int ds = 0, dd = 0;
    for (int c = 0; c < NCHUNK; ++c) {
        ds += cnt_s[(r * NCHUNK + c) * R + ip];
        dd += cnt_d[(r * NCHUNK + c) * R + ip];
    }
    degd_sum[i] = dd;
    if (i < n) {
        onrm[i] = rsqrtf((float)max(ds, 1));
        inrm[i] = rsqrtf((float)max(dd, 1));
    }
    // block-wide sum of dd
    red[tid] = dd;
    __syncthreads();
#pragma unroll
    for (int off = 128; off > 0; off >>= 1) {
        if (tid < off) red[tid] += red[tid + off];
        __syncthreads();
    }
    if (tid == 0) blocksum[blockIdx.x] = red[0];
}

// Fused parallel scan + cursor bases.
__global__ __launch_bounds__(256) void k_cursors2(const int* __restrict__ blocksum, int nblk,
                                                  const int* __restrict__ degd_sum,
                                                  const unsigned short* __restrict__ cnt_d, int R,
                                                  int* __restrict__ row_ptr,
                                                  int* __restrict__ cbase, int total_i) {
    __shared__ int bs[256];
    __shared__ int wsum[4];
    int tid = threadIdx.x;
    bs[tid] = (tid < nblk) ? blocksum[tid] : 0;
    __syncthreads();
#pragma unroll
    for (int off = 1; off < 256; off <<= 1) {
        int v = bs[tid];
        int u = (tid >= off) ? bs[tid - off] : 0;
        __syncthreads();
        bs[tid] = v + u;
        __syncthreads();
    }
    int base = (blockIdx.x > 0) ? bs[blockIdx.x - 1] : 0;

    int i = blockIdx.x * 256 + tid;
    int dd = degd_sum[i];
    int lane = tid & 63, wid = tid >> 6;
    int x = dd;
#pragma unroll
    for (int off = 1; off < 64; off <<= 1) {
        int y = __shfl_up(x, off, 64);
        if (lane >= off) x += y;
    }
    if (lane == 63) wsum[wid] = x;
    __syncthreads();
    int wbase = 0;
    for (int wp = 0; wp < wid; ++wp) wbase += wsum[wp];
    int excl = base + wbase + (x - dd);
    row_ptr[i] = excl;
    if (i == total_i - 1) row_ptr[total_i] = excl + dd;

    int r = i / R, ip = i - r * R;
    int run = excl;
    for (int c = 0; c < NCHUNK; ++c) {
        int idx = (r * NCHUNK + c) * R + ip;
        cbase[idx] = run;
        run += cnt_d[idx];
    }
}

__global__ void k_csr_scatter(const int* __restrict__ src,
                              const int* __restrict__ dst,
                              const unsigned short* __restrict__ pos,
                              const int* __restrict__ cbase,
                              int ne, int R, int E,
                              int* __restrict__ eidx) {
    int i = blockIdx.x * blockDim.x + threadIdx.x;
    if (i >= ne) return;
    int d = dst[i];
    int r = d / R, ip = d - r * R;
    int c = i / E;
    eidx[cbase[(r * NCHUNK + c) * R + ip] + pos[i]] = src[i];
}

// ---------------------------------------------------------------------------
// Weight split (standalone — only used on the legacy preprocessing path)
// ---------------------------------------------------------------------------

__global__ void k_split_w_all(const float* __restrict__ W0, const float* __restrict__ W1,
                              const float* __restrict__ W2, const float* __restrict__ W3,
                              unsigned short* __restrict__ Wh0, unsigned short* __restrict__ Wl0,
                              unsigned short* __restrict__ Wh1, unsigned short* __restrict__ Wl1,
                              unsigned short* __restrict__ Wh2, unsigned short* __restrict__ Wl2,
                              unsigned short* __restrict__ Wh3, unsigned short* __restrict__ Wl3) {
    int i = blockIdx.x * blockDim.x + threadIdx.x;
    const float* W; unsigned short *Wh, *Wl; int K, F, off;
    if (i < 32768)                    { W = W0; Wh = Wh0; Wl = Wl0; K = 256; F = 128; off = i; }
    else if (i < 32768 + 16384)       { W = W1; Wh = Wh1; Wl = Wl1; K = 128; F = 128; off = i - 32768; }
    else if (i < 32768 + 32768)       { W = W2; Wh = Wh2; Wl = Wl2; K = 128; F = 128; off = i - 49152; }
    else if (i < 32768 + 32768 + 8192){ W = W3; Wh = Wh3; Wl = Wl3; K = 128; F = 64;  off = i - 65536; }
    else return;
    int k = off / F, c = off % F;
    unsigned short h, l;
    split_bf16(W[k * F + c], h, l);
    Wh[c * K + k] = h;
    Wl[c * K + k] = l;
}

// ---------------------------------------------------------------------------
// MFMA GEMM: H[m][c] = sum_k A[m][k]*W[k][c]; H stored fp16.
// BM=128, KT=128, full-N (R2 tiling). PER-KT A-PANEL REGISTER PREFETCH:
// all A-loads for the kt (16 x 16B non-FA; 16 x float4-pairs FA) are issued
// back-to-back BEFORE the B-staging barrier -> one batched HBM round trip,
// register-resident MFMA loop. Values and per-acc MFMA k-order identical to
// the per-k0-load version (bit-exact).
// FA=true: A read from fp32 X, *onrm + bf16 split fused (into the prefetch).
// ---------------------------------------------------------------------------
template <int K, int N, bool FA>
__global__ __launch_bounds__(256) void k_mm(const unsigned short* __restrict__ Ah,
                                            const unsigned short* __restrict__ Al,
                                            const float* __restrict__ Xf,
                                            const float* __restrict__ onrm,
                                            const unsigned short* __restrict__ Bh,
                                            const unsigned short* __restrict__ Bl,
                                            __half* __restrict__ H, int n) {
    constexpr int KT = 128;
    constexpr int NT = N / 16;
    constexpr int NKT = K / KT;
    __shared__ unsigned short sBh[N * KT];
    __shared__ unsigned short sBl[N * KT];

    int tid = threadIdx.x;
    int w = tid >> 6, lane = tid & 63;
    int quad = lane >> 4, l16 = lane & 15;
    int row_base = blockIdx.x * 128 + w * 32;

    int ar0 = row_base + l16;
    int ar1 = row_base + 16 + l16;
    if (ar0 >= n) ar0 = n - 1;
    if (ar1 >= n) ar1 = n - 1;

    float on0 = 0.f, on1 = 0.f;
    if (FA) { on0 = onrm[ar0]; on1 = onrm[ar1]; }

    f32x4 acc[2][NT];
#pragma unroll
    for (int m = 0; m < 2; ++m)
#pragma unroll
        for (int t = 0; t < NT; ++t) acc[m][t] = (f32x4){0.f, 0.f, 0.f, 0.f};

    for (int kt = 0; kt < NKT; ++kt) {
        // ---- A-panel register prefetch for this kt: batched independent loads
        short8 pa0h[4], pa0l[4], pa1h[4], pa1l[4];
        if (!FA) {
#pragma unroll
            for (int ph = 0; ph < 4; ++ph) {
                int eoff = kt * KT + ph * 32 + quad * 8;
                pa0h[ph] = *(const short8*)(Ah + (size_t)ar0 * K + eoff);
                pa0l[ph] = *(const short8*)(Al + (size_t)ar0 * K + eoff);
                pa1h[ph] = *(const short8*)(Ah + (size_t)ar1 * K + eoff);
                pa1l[ph] = *(const short8*)(Al + (size_t)ar1 * K + eoff);
            }
        } else {
            // 16 float4 loads issued back-to-back, then split+scale into regs
            float4 px0[8], px1[8];
#pragma unroll
            for (int ph = 0; ph < 4; ++ph) {
                int eoff = kt * KT + ph * 32 + quad * 8;
                const float* x0 = Xf + (size_t)ar0 * K + eoff;
                const float* x1 = Xf + (size_t)ar1 * K + eoff;
                px0[2 * ph]     = *(const float4*)x0;
                px0[2 * ph + 1] = *(const float4*)(x0 + 4);
                px1[2 * ph]     = *(const float4*)x1;
                px1[2 * ph + 1] = *(const float4*)(x1 + 4);
            }
#pragma unroll
            for (int ph = 0; ph < 4; ++ph) {
                float e0[8] = {px0[2*ph].x, px0[2*ph].y, px0[2*ph].z, px0[2*ph].w,
                               px0[2*ph+1].x, px0[2*ph+1].y, px0[2*ph+1].z, px0[2*ph+1].w};
                float e1[8] = {px1[2*ph].x, px1[2*ph].y, px1[2*ph].z, px1[2*ph].w,
                               px1[2*ph+1].x, px1[2*ph+1].y, px1[2*ph+1].z, px1[2*ph+1].w};
#pragma unroll
                for (int q = 0; q < 8; ++q) {
                    unsigned short hh, ll;
                    split_bf16(e0[q] * on0, hh, ll);
                    pa0h[ph][q] = (short)hh; pa0l[ph][q] = (short)ll;
                    split_bf16(e1[q] * on1, hh, ll);
                    pa1h[ph][q] = (short)hh; pa1l[ph][q] = (short)ll;
                }
            }
        }

        if (kt) __syncthreads();
        for (int idx = tid; idx < N * 16; idx += 256) {
            int c = idx >> 4;
            int g = idx & 15;
            short8 vh = *(const short8*)(Bh + (size_t)c * K + kt * KT + g * 8);
            short8 vl = *(const short8*)(Bl + (size_t)c * K + kt * KT + g * 8);
            int sg = g ^ (c & 15);
            *(short8*)(&sBh[c * KT + sg * 8]) = vh;
            *(short8*)(&sBl[c * KT + sg * 8]) = vl;
        }
        __syncthreads();

#pragma unroll
        for (int k0 = 0; k0 < KT; k0 += 32) {
            int ph = k0 >> 5;                  // 0..3, static after unroll
            short8 a0hv = pa0h[ph], a0lv = pa0l[ph];
            short8 a1hv = pa1h[ph], a1lv = pa1l[ph];
            int g = (k0 >> 3) + quad;
            int sg8 = (g ^ l16) * 8;
#pragma unroll
            for (int t = 0; t < NT; ++t) {
                int cb = (t * 16 + l16) * KT;
                short8 bh = *(const short8*)(&sBh[cb + sg8]);
                short8 bl = *(const short8*)(&sBl[cb + sg8]);
                acc[0][t] = __builtin_amdgcn_mfma_f32_16x16x32_bf16(a0hv, bh, acc[0][t], 0, 0, 0);
                acc[0][t] = __builtin_amdgcn_mfma_f32_16x16x32_bf16(a0lv, bh, acc[0][t], 0, 0, 0);
                acc[0][t] = __builtin_amdgcn_mfma_f32_16x16x32_bf16(a0hv, bl, acc[0][t], 0, 0, 0);
                acc[1][t] = __builtin_amdgcn_mfma_f32_16x16x32_bf16(a1hv, bh, acc[1][t], 0, 0, 0);
                acc[1][t] = __builtin_amdgcn_mfma_f32_16x16x32_bf16(a1lv, bh, acc[1][t], 0, 0, 0);
                acc[1][t] = __builtin_amdgcn_mfma_f32_16x16x32_bf16(a1hv, bl, acc[1][t], 0, 0, 0);
            }
        }
    }

#pragma unroll
    for (int m = 0; m < 2; ++m) {
#pragma unroll
        for (int t = 0; t < NT; ++t) {
#pragma unroll
            for (int r = 0; r < 4; ++r) {
                int grow = row_base + m * 16 + quad * 4 + r;
                if (grow < n) H[(size_t)grow * N + t * 16 + l16] = __float2half(acc[m][t][r]);
            }
        }
    }
}

// ---------------------------------------------------------------------------
// Aggregation: 16-lane row segments, 4 nodes/wave (best-measured R2 config).
// ---------------------------------------------------------------------------

__global__ __launch_bounds__(256) void k_agg128_split(const __half* __restrict__ h,
                                                      const int* __restrict__ row_ptr,
                                                      const int* __restrict__ eidx,
                                                      const float* __restrict__ inrm,
                                                      const float* __restrict__ onrm,
                                                      const float* __restrict__ bias,
                                                      unsigned short* __restrict__ Ah,
                                                      unsigned short* __restrict__ Al, int n) {
    int wave = threadIdx.x >> 6;
    int lane = threadIdx.x & 63;
    int g = lane >> 4;
    int l = lane & 15;
    int node = blockIdx.x * 16 + wave * 4 + g;
    bool valid = node < n;
    int nd = valid ? node : n - 1;
    int beg = row_ptr[nd], end = row_ptr[nd + 1];
    const short8* h8 = (const short8*)h;   // row = 16 granules of 16B

    float a[4][8];
#pragma unroll
    for (int u = 0; u < 4; ++u)
#pragma unroll
        for (int c = 0; c < 8; ++c) a[u][c] = 0.f;

    int j = beg;
    for (; j + 4 <= end; j += 4) {
        int s[4];
#pragma unroll
        for (int u = 0; u < 4; ++u) s[u] = eidx[j + u];
        short8 v[4];
#pragma unroll
        for (int u = 0; u < 4; ++u) v[u] = h8[(size_t)s[u] * 16 + l];
#pragma unroll
        for (int u = 0; u < 4; ++u) {
            const __half2* ph = reinterpret_cast<const __half2*>(&v[u]);
#pragma unroll
            for (int p = 0; p < 4; ++p) {
                float2 f = __half22float2(ph[p]);
                a[u][2 * p] += f.x;
                a[u][2 * p + 1] += f.y;
            }
        }
    }
    for (; j < end; ++j) {
        short8 v = h8[(size_t)eidx[j] * 16 + l];
        const __half2* ph = reinterpret_cast<const __half2*>(&v);
#pragma unroll
        for (int p = 0; p < 4; ++p) {
            float2 f = __half22float2(ph[p]);
            a[0][2 * p] += f.x;
            a[0][2 * p + 1] += f.y;
        }
    }

    float nrm = inrm[nd];
    float on = onrm[nd];
    float4 b0 = ((const float4*)bias)[l * 2];
    float4 b1 = ((const float4*)bias)[l * 2 + 1];
    float bb[8] = {b0.x, b0.y, b0.z, b0.w, b1.x, b1.y, b1.z, b1.w};
    short8 hv, lv;
#pragma unroll
    for (int c = 0; c < 8; ++c) {
        float s = (a[0][c] + a[1][c]) + (a[2][c] + a[3][c]);
        float o = fmaxf(s * nrm + bb[c], 0.f) * on;
        unsigned short hh, ll;
        split_bf16(o, hh, ll);
        hv[c] = (short)hh;
        lv[c] = (short)ll;
    }
    if (valid) {
        ((short8*)Ah)[(size_t)node * 16 + l] = hv;
        ((short8*)Al)[(size_t)node * 16 + l] = lv;
    }
}

// FO=64 final layer: 16-lane x 8B segments (4 nodes/wave), unroll 8, fp32 out.
__global__ __launch_bounds__(256) void k_agg64(const __half* __restrict__ h,
                                               const int* __restrict__ row_ptr,
                                               const int* __restrict__ eidx,
                                               const float* __restrict__ inrm,
                                               const float* __restrict__ bias,
                                               float* __restrict__ out, int n) {
    int wave = threadIdx.x >> 6;
    int lane = threadIdx.x & 63;
    int g = lane >> 4;
    int l = lane & 15;
    int node = blockIdx.x * 16 + wave * 4 + g;
    bool valid = node < n;
    int nd = valid ? node : n - 1;
    int beg = row_ptr[nd], end = row_ptr[nd + 1];
    const ushort4* h4 = (const ushort4*)h;  // row = 16 granules of 8B

    float a[8][4];
#pragma unroll
    for (int u = 0; u < 8; ++u)
#pragma unroll
        for (int c = 0; c < 4; ++c) a[u][c] = 0.f;

    int j = beg;
    for (; j + 8 <= end; j += 8) {
        int s[8];
#pragma unroll
        for (int u = 0; u < 8; ++u) s[u] = eidx[j + u];
        ushort4 v[8];
#pragma unroll
        for (int u = 0; u < 8; ++u) v[u] = h4[(size_t)s[u] * 16 + l];
#pragma unroll
        for (int u = 0; u < 8; ++u) {
            const __half2* ph = reinterpret_cast<const __half2*>(&v[u]);
            float2 f0 = __half22float2(ph[0]);
            float2 f1 = __half22float2(ph[1]);
            a[u][0] += f0.x; a[u][1] += f0.y; a[u][2] += f1.x; a[u][3] += f1.y;
        }
    }
    for (; j < end; ++j) {
        ushort4 v = h4[(size_t)eidx[j] * 16 + l];
        const __half2* ph = reinterpret_cast<const __half2*>(&v);
        float2 f0 = __half22float2(ph[0]);
        float2 f1 = __half22float2(ph[1]);
        a[0][0] += f0.x; a[0][1] += f0.y; a[0][2] += f1.x; a[0][3] += f1.y;
    }

    float nrm = inrm[nd];
    float4 b4 = ((const float4*)bias)[l];
    float4 o;
    float s0 = ((a[0][0] + a[1][0]) + (a[2][0] + a[3][0])) + ((a[4][0] + a[5][0]) + (a[6][0] + a[7][0]));
    float s1 = ((a[0][1] + a[1][1]) + (a[2][1] + a[3][1])) + ((a[4][1] + a[5][1]) + (a[6][1] + a[7][1]));
    float s2 = ((a[0][2] + a[1][2]) + (a[2][2] + a[3][2])) + ((a[4][2] + a[5][2]) + (a[6][2] + a[7][2]));
    float s3 = ((a[0][3] + a[1][3]) + (a[2][3] + a[3][3])) + ((a[4][3] + a[5][3]) + (a[6][3] + a[7][3]));
    o.x = s0 * nrm + b4.x;
    o.y = s1 * nrm + b4.y;
    o.z = s2 * nrm + b4.z;
    o.w = s3 * nrm + b4.w;
    if (valid) ((float4*)out)[(size_t)node * 16 + l] = o;
}

// ---------------------------------------------------------------------------
// Legacy single-block scan (only for fallback path)
// ---------------------------------------------------------------------------
__global__ __launch_bounds__(1024) void k_scan(const int* __restrict__ deg, int n,
                                               int* __restrict__ row_ptr) {
    __shared__ int wsum[16];
    __shared__ int carry;
    int tid = threadIdx.x;
    int lane = tid & 63;
    int wid = tid >> 6;
    if (tid == 0) carry = 0;
    __syncthreads();
    int n4 = (n + 3) >> 2;
    for (int base = 0; base < n4; base += 1024) {
        int i4 = base + tid;
        int4 v = make_int4(0, 0, 0, 0);
        if (i4 < n4) v = ((const int4*)deg)[i4];
        int s = v.x + v.y + v.z + v.w;
        int x = s;
#pragma unroll
        for (int off = 1; off < 64; off <<= 1) {
            int y = __shfl_up(x, off, 64);
            if (lane >= off) x += y;
        }
        if (lane == 63) wsum[wid] = x;
        __syncthreads();
        if (wid == 0 && lane < 16) {
            int w = wsum[lane];
#pragma unroll
            for (int off = 1; off < 16; off <<= 1) {
                int y = __shfl_up(w, off, 16);
                if (lane >= off) w += y;
            }
            wsum[lane] = w;
        }
        __syncthreads();
        int excl = x - s + carry + (wid > 0 ? wsum[wid - 1] : 0);
        if (i4 < n4) {
            int e0 = excl, e1 = e0 + v.x, e2 = e1 + v.y, e3 = e2 + v.z;
            ((int4*)row_ptr)[i4] = make_int4(e0, e1, e2, e3);
        }
        __syncthreads();
        if (tid == 0) carry += wsum[15];
        __syncthreads();
    }
    if (tid == 0) row_ptr[n] = carry;
}

// ---------------------------------------------------------------------------
// Fallback fp32 path (known-good) — used if workspace too small for MFMA path.
// ---------------------------------------------------------------------------
template <int K, int FO, int TX, int TY, int RPT>
__global__ __launch_bounds__(256) void k_matmul(const float* __restrict__ X,
                                                const float* __restrict__ W,
                                                const float* __restrict__ onrm,
                                                float* __restrict__ H, int n) {
    constexpr int BROWS = TY * RPT;
    constexpr int LDK = K + 1;
    __shared__ float xs[BROWS * LDK];
    int tx = threadIdx.x, ty = threadIdx.y;
    int tid = ty * TX + tx;
    int row0 = blockIdx.x * BROWS;

    for (int idx = tid; idx < BROWS * K; idx += 256) {
        int r = idx / K;
        int k = idx - r * K;
        int row = row0 + r;
        xs[r * LDK + k] = (row < n) ? X[(size_t)row * K + k] : 0.f;
    }
    __syncthreads();

    float4 acc[RPT];
#pragma unroll
    for (int r = 0; r < RPT; ++r) acc[r] = make_float4(0.f, 0.f, 0.f, 0.f);

    const float4* W4 = (const float4*)W;
#pragma unroll 4
    for (int k = 0; k < K; ++k) {
        float4 w = W4[k * (FO / 4) + tx];
#pragma unroll
        for (int r = 0; r < RPT; ++r) {
            float xv = xs[(ty * RPT + r) * LDK + k];
            acc[r].x += xv * w.x;
            acc[r].y += xv * w.y;
            acc[r].z += xv * w.z;
            acc[r].w += xv * w.w;
        }
    }

#pragma unroll
    for (int r = 0; r < RPT; ++r) {
        int row = row0 + ty * RPT + r;
        if (row < n) {
            float s = onrm[row];
            float4 o = make_float4(acc[r].x * s, acc[r].y * s, acc[r].z * s, acc[r].w * s);
            ((float4*)H)[(size_t)row * (FO / 4) + tx] = o;
        }
    }
}

__global__ __launch_bounds__(256) void k_agg128f(const float* __restrict__ h,
                                                 const int* __restrict__ row_ptr,
                                                 const int* __restrict__ eidx,
                                                 const float* __restrict__ inrm,
                                                 const float* __restrict__ bias,
                                                 float* __restrict__ out, int n, int relu) {
    int node = blockIdx.x * 4 + (threadIdx.x >> 6);
    int lane = threadIdx.x & 63;
    if (node >= n) return;
    int beg = row_ptr[node], end = row_ptr[node + 1];
    const float2* h2 = (const float2*)h;
    float ax = 0.f, ay = 0.f;
    for (int j = beg; j < end; ++j) {
        int s = eidx[j];
        float2 v = h2[(size_t)s * 64 + lane];
        ax += v.x;
        ay += v.y;
    }
    float nrm = inrm[node];
    float2 b2 = ((const float2*)bias)[lane];
    float ox = ax * nrm + b2.x;
    float oy = ay * nrm + b2.y;
    if (relu) { ox = fmaxf(ox, 0.f); oy = fmaxf(oy, 0.f); }
    float2 o; o.x = ox; o.y = oy;
    ((float2*)out)[(size_t)node * 64 + lane] = o;
}

__global__ __launch_bounds__(256) void k_agg64f(const float* __restrict__ h,
                                                const int* __restrict__ row_ptr,
                                                const int* __restrict__ eidx,
                                                const float* __restrict__ inrm,
                                                const float* __restrict__ bias,
                                                float* __restrict__ out, int n) {
    int node = blockIdx.x * 4 + (threadIdx.x >> 6);
    int lane = threadIdx.x & 63;
    if (node >= n) return;
    int beg = row_ptr[node], end = row_ptr[node + 1];
    float acc = 0.f;
    for (int j = beg; j < end; ++j) {
        int s = eidx[j];
        acc += h[(size_t)s * 64 + lane];
    }
    out[(size_t)node * 64 + lane] = acc * inrm[node] + bias[lane];
}

// Legacy atomic preprocessing (fallback only)
__global__ void k_degrees_leg(const int* __restrict__ src, const int* __restrict__ dst,
                              int ne, int* __restrict__ degs, int* __restrict__ degd) {
    int i = blockIdx.x * blockDim.x + threadIdx.x;
    if (i < ne) {
        atomicAdd(&degs[src[i]], 1);
        atomicAdd(&degd[dst[i]], 1);
    }
}
__global__ void k_norms_leg(const int* __restrict__ degs, const int* __restrict__ degd,
                            float* __restrict__ onrm, float* __restrict__ inrm,
                            int* __restrict__ degd_sum, int n) {
    int i = blockIdx.x * blockDim.x + threadIdx.x;
    if (i < n) {
        degd_sum[i] = degd[i];
        onrm[i] = rsqrtf((float)max(degs[i], 1));
        inrm[i] = rsqrtf((float)max(degd[i], 1));
    }
}
__global__ void k_copy_int(const int* __restrict__ a, int* __restrict__ b, int n) {
    int i = blockIdx.x * blockDim.x + threadIdx.x;
    if (i < n) b[i] = a[i];
}
__global__ void k_build_csr_leg(const int* __restrict__ src, const int* __restrict__ dst,
                                int ne, int* __restrict__ cursor, int* __restrict__ eidx) {
    int i = blockIdx.x * blockDim.x + threadIdx.x;
    if (i < ne) {
        int p = atomicAdd(&cursor[dst[i]], 1);
        eidx[p] = src[i];
    }
}

static inline size_t align_up(size_t v, size_t a) { return (v + a - 1) & ~(a - 1); }

extern "C" void kernel_launch(void* const* d_in, const int* in_sizes, int n_in,
                              void* d_out, int out_size, void* d_ws, size_t ws_size,
                              hipStream_t stream) {
    const float* x  = (const float*)d_in[0];
    const int* ei   = (const int*)d_in[1];
    const float* W0 = (const float*)d_in[2];
    const float* b0 = (const float*)d_in[3];
    const float* W1 = (const float*)d_in[4];
    const float* b1 = (const float*)d_in[5];
    const float* W2 = (const float*)d_in[6];
    const float* b2 = (const float*)d_in[7];
    const float* W3 = (const float*)d_in[8];
    const float* b3 = (const float*)d_in[9];

    const int n  = in_sizes[0] / 256;   // 50000
    const int ne = in_sizes[1] / 2;     // 800000
    const int n_pad = (n + 127) & ~127;
    const int* src = ei;
    const int* dst = ei + ne;

    const int R = ((n + NRANGE * 64 - 1) / (NRANGE * 64)) * 64;   // 6272 for n=50000
    const int E = (ne + NCHUNK - 1) / NCHUNK;                     // 6250
    const int nscan = NRANGE * R;                                 // 50176
    const bool fast_pre = (R <= RMAX) && (E <= 65535);

    // ---- shared layout ----
    char* ws = (char*)d_ws;
    size_t off = 0;
    auto take = [&](size_t bytes) { void* p = ws + off; off = align_up(off + bytes, 256); return p; };
    int* row_ptr  = (int*)take((size_t)(nscan + 8) * 4);   // indexed to nscan by k_cursors2
    int* degd_sum = (int*)take((size_t)nscan * 4);         // indexed to nscan-1
    int* eidx     = (int*)take((size_t)ne * 4);
    float* onrm   = (float*)take((size_t)n * 4);
    float* inrm   = (float*)take((size_t)n * 4);

    // ---- MFMA-path layout ----
    size_t off_save = off;
    unsigned short* Ah  = (unsigned short*)take((size_t)n_pad * 256 * 2);
    unsigned short* Al  = (unsigned short*)take((size_t)n_pad * 256 * 2);
    __half* hbuf        = (__half*)take((size_t)n * 128 * 2);
    unsigned short* Wh0 = (unsigned short*)take(256 * 128 * 2);
    unsigned short* Wl0 = (unsigned short*)take(256 * 128 * 2);
    unsigned short* Wh1 = (unsigned short*)take(128 * 128 * 2);
    unsigned short* Wl1 = (unsigned short*)take(128 * 128 * 2);
    unsigned short* Wh2 = (unsigned short*)take(128 * 128 * 2);
    unsigned short* Wl2 = (unsigned short*)take(128 * 128 * 2);
    unsigned short* Wh3 = (unsigned short*)take(128 * 64 * 2);
    unsigned short* Wl3 = (unsigned short*)take(128 * 64 * 2);
    bool use_mfma = (off <= ws_size);

    // ---- preprocessing scratch ALIASED onto Ah/Al/hbuf (dead until mm0) ----
    char* pre = (char*)Ah;
    const size_t cntSz = align_up((size_t)NRANGE * NCHUNK * R * 2, 256);
    unsigned short* cnt_s = (unsigned short*)pre;
    unsigned short* cnt_d = (unsigned short*)(pre + cntSz);
    int* cbase            = (int*)(pre + 2 * cntSz);
    unsigned short* pos   = (unsigned short*)(pre + 4 * cntSz);
    int* blocksum         = (int*)(pre + 4 * cntSz + align_up((size_t)ne * 2, 256));

    const int aggGrid = (n + 15) / 16;

    if (fast_pre) {
        // ---- LDS-privatized preprocessing: zero global atomics ----
        const int nblk = nscan / 256;                   // 196 (<=256 required)
        const int wsplitBlocks = use_mfma ? 288 : 0;    // 73728/256
        k_hist<<<NRANGE * NCHUNK + wsplitBlocks, 256, 0, stream>>>(
            src, dst, ne, R, E, cnt_s, cnt_d, pos,
            W0, W1, W2, W3, Wh0, Wl0, Wh1, Wl1, Wh2, Wl2, Wh3, Wl3);
        k_reduce_norms<<<nblk, 256, 0, stream>>>(cnt_s, cnt_d, R, n,
                                                 onrm, inrm, degd_sum, blocksum);
        k_cursors2<<<nblk, 256, 0, stream>>>(blocksum, nblk, degd_sum, cnt_d, R,
                                             row_ptr, cbase, nscan);
        k_csr_scatter<<<(ne + 255) / 256, 256, 0, stream>>>(src, dst, pos, cbase, ne, R, E, eidx);
    } else {
        int* degs   = (int*)pre;
        int* degd   = (int*)pre + n_pad;
        int* cursor = (int*)pre + 2 * n_pad;
        hipMemsetAsync(degs, 0, (size_t)2 * n_pad * 4, stream);
        k_degrees_leg<<<(ne + 255) / 256, 256, 0, stream>>>(src, dst, ne, degs, degd);
        k_norms_leg<<<(n + 255) / 256, 256, 0, stream>>>(degs, degd, onrm, inrm, degd_sum, n);
        k_scan<<<1, 1024, 0, stream>>>(degd_sum, n, row_ptr);
        k_copy_int<<<(n + 255) / 256, 256, 0, stream>>>(row_ptr, cursor, n);
        k_build_csr_leg<<<(ne + 255) / 256, 256, 0, stream>>>(src, dst, ne, cursor, eidx);
        if (use_mfma)
            k_split_w_all<<<(73728 + 255) / 256, 256, 0, stream>>>(
                W0, W1, W2, W3, Wh0, Wl0, Wh1, Wl1, Wh2, Wl2, Wh3, Wl3);
    }

    if (use_mfma) {
        const int mmGrid = n_pad / 128;
        // L0: 256 -> 128, A = x fp32 (split fused, onrm folded)
        k_mm<256, 128, true><<<mmGrid, 256, 0, stream>>>(nullptr, nullptr, x, onrm, Wh0, Wl0, hbuf, n);
        k_agg128_split<<<aggGrid, 256, 0, stream>>>(hbuf, row_ptr, eidx, inrm, onrm, b0, Ah, Al, n);
        // L1
        k_mm<128, 128, false><<<mmGrid, 256, 0, stream>>>(Ah, Al, nullptr, nullptr, Wh1, Wl1, hbuf, n);
        k_agg128_split<<<aggGrid, 256, 0, stream>>>(hbuf, row_ptr, eidx, inrm, onrm, b1, Ah, Al, n);
        // L2
        k_mm<128, 128, false><<<mmGrid, 256, 0, stream>>>(Ah, Al, nullptr, nullptr, Wh2, Wl2, hbuf, n);
        k_agg128_split<<<aggGrid, 256, 0, stream>>>(hbuf, row_ptr, eidx, inrm, onrm, b2, Ah, Al, n);
        // L3: 128 -> 64
        k_mm<128, 64, false><<<mmGrid, 256, 0, stream>>>(Ah, Al, nullptr, nullptr, Wh3, Wl3, hbuf, n);
        k_agg64<<<aggGrid, 256, 0, stream>>>(hbuf, row_ptr, eidx, inrm, b3, (float*)d_out, n);
    } else {
        // fp32 fallback
        off = off_save;
        float* hbufF  = (float*)take((size_t)n * 128 * 4);
        float* xnextF = (float*)take((size_t)n * 128 * 4);
        const int aggGridF = (n + 3) / 4;

        k_matmul<256, 128, 32, 8, 4><<<(n + 31) / 32, dim3(32, 8), 0, stream>>>(x, W0, onrm, hbufF, n);
        k_agg128f<<<aggGridF, 256, 0, stream>>>(hbufF, row_ptr, eidx, inrm, b0, xnextF, n, 1);
        k_matmul<128, 128, 32, 8, 4><<<(n + 31) / 32, dim3(32, 8), 0, stream>>>(xnextF, W1, onrm, hbufF, n);
        k_agg128f<<<aggGridF, 256, 0, stream>>>(hbufF, row_ptr, eidx, inrm, b1, xnextF, n, 1);
        k_matmul<128, 128, 32, 8, 4><<<(n + 31) / 32, dim3(32, 8), 0, stream>>>(xnextF, W2, onrm, hbufF, n);
        k_agg128f<<<aggGridF, 256, 0, stream>>>(hbufF, row_ptr, eidx, inrm, b2, xnextF, n, 1);
        k_matmul<128, 64, 16, 16, 4><<<(n + 63) / 64, dim3(16, 16), 0, stream>>>(xnextF, W3, onrm, hbufF, n);
        k_agg64f<<<aggGridF, 256, 0, stream>>>(hbufF, row_ptr, eidx, inrm, b3, (float*)d_out, n);
    }
}

// Round 9
// 332.961 us; speedup vs baseline: 1.1459x; 1.0124x over previous
//
#include <hip/hip_runtime.h>
#include <hip/hip_fp16.h>

// ---------------------------------------------------------------------------
// GCN 4-layer forward on MI355X (gfx950).
//   Preprocess (ZERO global atomics): LDS range histograms (8 ranges x 128
//     chunks, PACKED 16-bit counters -> 25KB LDS) + per-edge bucket rank ->
//     reduce+norms -> parallel hierarchical scan fused into cursor kernel ->
//     single-pass CSR scatter. Chunk-co-located XCD swizzle for edge L2 reuse.
//     Weight split rides as extra blocks on k_hist's grid.
//   GEMMs: bf16-split MFMA (3-term, ~fp32 precision), BM=128/KT=128/full-N,
//     512-THREAD BLOCKS: 8 waves x 16-row strips (was 4 x 32) -> 2x resident
//     waves at identical traffic/LDS (grid-limited regime: 392 blocks,
//     LDS-capped 2 blocks/CU -> waves/block is the only occupancy lever).
//     Per-kt whole-panel A register prefetch (batched HBM round trip).
//   h in fp16 -> CSR gather with 16-lane/16B row segments (4 nodes/wave),
//     fused epilogue + bf16 hi/lo split.
// ---------------------------------------------------------------------------

typedef __attribute__((ext_vector_type(8))) short short8;
typedef __attribute__((ext_vector_type(4))) float f32x4;

#define NRANGE 8
#define NCHUNK 128
#define RMAX   6272   // 8*6272 = 50176 >= 50000 nodes; LDS = 2*(6272/2)*4 = 25088 B

__device__ inline unsigned short bf16_rne(float v) {
    union { float f; unsigned u; } c; c.f = v;
    unsigned u = c.u;
    unsigned lsb = (u >> 16) & 1u;
    u += 0x7fffu + lsb;
    return (unsigned short)(u >> 16);
}
__device__ inline float bf16_to_f(unsigned short h) {
    union { unsigned u; float f; } c; c.u = ((unsigned)h) << 16;
    return c.f;
}
__device__ inline void split_bf16(float v, unsigned short& hi, unsigned short& lo) {
    hi = bf16_rne(v);
    lo = bf16_rne(v - bf16_to_f(hi));
}

// ---------------------------------------------------------------------------
// Preprocessing — LDS-privatized histograms, packed 16-bit counters.
// ---------------------------------------------------------------------------

__global__ __launch_bounds__(256) void k_hist(const int* __restrict__ src,
                                              const int* __restrict__ dst,
                                              int ne, int R, int E,
                                              unsigned short* __restrict__ cnt_s,
                                              unsigned short* __restrict__ cnt_d,
                                              unsigned short* __restrict__ pos,
                                              const float* __restrict__ W0,
                                              const float* __restrict__ W1,
                                              const float* __restrict__ W2,
                                              const float* __restrict__ W3,
                                              unsigned short* __restrict__ Wh0, unsigned short* __restrict__ Wl0,
                                              unsigned short* __restrict__ Wh1, unsigned short* __restrict__ Wl1,
                                              unsigned short* __restrict__ Wh2, unsigned short* __restrict__ Wl2,
                                              unsigned short* __restrict__ Wh3, unsigned short* __restrict__ Wl3) {
    __shared__ int hs32[RMAX / 2];
    __shared__ int hd32[RMAX / 2];
    if (blockIdx.x >= NRANGE * NCHUNK) {
        // ---- weight split tail blocks (288 blocks x 256 = 73728 elements) ----
        int i = (blockIdx.x - NRANGE * NCHUNK) * 256 + threadIdx.x;
        const float* W; unsigned short *Wh, *Wl; int K, F, off;
        if (i < 32768)                     { W = W0; Wh = Wh0; Wl = Wl0; K = 256; F = 128; off = i; }
        else if (i < 32768 + 16384)        { W = W1; Wh = Wh1; Wl = Wl1; K = 128; F = 128; off = i - 32768; }
        else if (i < 32768 + 32768)        { W = W2; Wh = Wh2; Wl = Wl2; K = 128; F = 128; off = i - 49152; }
        else if (i < 32768 + 32768 + 8192) { W = W3; Wh = Wh3; Wl = Wl3; K = 128; F = 64;  off = i - 65536; }
        else return;
        int k = off / F, c = off % F;
        unsigned short h, l;
        split_bf16(W[k * F + c], h, l);
        Wh[c * K + k] = h;
        Wl[c * K + k] = l;
        return;
    }
    // chunk-major decode: c = bid % NCHUNK -> XCD = c % 8 (NCHUNK % 8 == 0),
    // so all 8 range-blocks of a chunk share one XCD's L2 for the edge reads.
    int c = blockIdx.x & (NCHUNK - 1);
    int r = blockIdx.x >> 7;
    int tid = threadIdx.x;
    int Rh = R >> 1;
    for (int i = tid; i < Rh; i += 256) { hs32[i] = 0; hd32[i] = 0; }
    __syncthreads();
    int lo = r * R;
    int e0 = c * E, e1 = min(e0 + E, ne);
    for (int i = e0 + tid; i < e1; i += 256) {
        int s = src[i], d = dst[i];
        unsigned ps = (unsigned)(s - lo);
        unsigned pd = (unsigned)(d - lo);
        if (ps < (unsigned)R)
            atomicAdd(&hs32[ps >> 1], 1 << ((ps & 1) << 4));
        if (pd < (unsigned)R) {
            int sh = (pd & 1) << 4;
            int old = atomicAdd(&hd32[pd >> 1], 1 << sh);
            pos[i] = (unsigned short)((old >> sh) & 0xffff);   // rank in bucket
        }
    }
    __syncthreads();
    int base2 = (r * NCHUNK + c) * Rh;
    int* cs32 = (int*)cnt_s;
    int* cd32 = (int*)cnt_d;
    for (int i = tid; i < Rh; i += 256) {
        cs32[base2 + i] = hs32[i];
        cd32[base2 + i] = hd32[i];
    }
}

// Reduce per-node degrees + norms, AND emit per-block (256-node) degree sums
// for the hierarchical scan. Grid must be exactly (NRANGE*R)/256 blocks.
__global__ __launch_bounds__(256) void k_reduce_norms(const unsigned short* __restrict__ cnt_s,
                                                      const unsigned short* __restrict__ cnt_d,
                                                      int R, int n,
                                                      float* __restrict__ onrm,
                                                      float* __restrict__ inrm,
                                                      int* __restrict__ degd_sum,
                                                      int* __restrict__ blocksum) {
    __shared__ int red[256];
    int tid = threadIdx.x;
    int i = blockIdx.x * 256 + tid;
    int r = i / R, ip = i - r * R;
    int ds = 0, dd = 0;
    for (int c = 0; c < NCHUNK; ++c) {
        ds += cnt_s[(r * NCHUNK + c) * R + ip];
        dd += cnt_d[(r * NCHUNK + c) * R + ip];
    }
    degd_sum[i] = dd;
    if (i < n) {
        onrm[i] = rsqrtf((float)max(ds, 1));
        inrm[i] = rsqrtf((float)max(dd, 1));
    }
    // block-wide sum of dd
    red[tid] = dd;
    __syncthreads();
#pragma unroll
    for (int off = 128; off > 0; off >>= 1) {
        if (tid < off) red[tid] += red[tid + off];
        __syncthreads();
    }
    if (tid == 0) blocksum[blockIdx.x] = red[0];
}

// Fused parallel scan + cursor bases.
__global__ __launch_bounds__(256) void k_cursors2(const int* __restrict__ blocksum, int nblk,
                                                  const int* __restrict__ degd_sum,
                                                  const unsigned short* __restrict__ cnt_d, int R,
                                                  int* __restrict__ row_ptr,
                                                  int* __restrict__ cbase, int total_i) {
    __shared__ int bs[256];
    __shared__ int wsum[4];
    int tid = threadIdx.x;
    bs[tid] = (tid < nblk) ? blocksum[tid] : 0;
    __syncthreads();
#pragma unroll
    for (int off = 1; off < 256; off <<= 1) {
        int v = bs[tid];
        int u = (tid >= off) ? bs[tid - off] : 0;
        __syncthreads();
        bs[tid] = v + u;
        __syncthreads();
    }
    int base = (blockIdx.x > 0) ? bs[blockIdx.x - 1] : 0;

    int i = blockIdx.x * 256 + tid;
    int dd = degd_sum[i];
    int lane = tid & 63, wid = tid >> 6;
    int x = dd;
#pragma unroll
    for (int off = 1; off < 64; off <<= 1) {
        int y = __shfl_up(x, off, 64);
        if (lane >= off) x += y;
    }
    if (lane == 63) wsum[wid] = x;
    __syncthreads();
    int wbase = 0;
    for (int wp = 0; wp < wid; ++wp) wbase += wsum[wp];
    int excl = base + wbase + (x - dd);
    row_ptr[i] = excl;
    if (i == total_i - 1) row_ptr[total_i] = excl + dd;

    int r = i / R, ip = i - r * R;
    int run = excl;
    for (int c = 0; c < NCHUNK; ++c) {
        int idx = (r * NCHUNK + c) * R + ip;
        cbase[idx] = run;
        run += cnt_d[idx];
    }
}

__global__ void k_csr_scatter(const int* __restrict__ src,
                              const int* __restrict__ dst,
                              const unsigned short* __restrict__ pos,
                              const int* __restrict__ cbase,
                              int ne, int R, int E,
                              int* __restrict__ eidx) {
    int i = blockIdx.x * blockDim.x + threadIdx.x;
    if (i >= ne) return;
    int d = dst[i];
    int r = d / R, ip = d - r * R;
    int c = i / E;
    eidx[cbase[(r * NCHUNK + c) * R + ip] + pos[i]] = src[i];
}

// ---------------------------------------------------------------------------
// Weight split (standalone — only used on the legacy preprocessing path)
// ---------------------------------------------------------------------------

__global__ void k_split_w_all(const float* __restrict__ W0, const float* __restrict__ W1,
                              const float* __restrict__ W2, const float* __restrict__ W3,
                              unsigned short* __restrict__ Wh0, unsigned short* __restrict__ Wl0,
                              unsigned short* __restrict__ Wh1, unsigned short* __restrict__ Wl1,
                              unsigned short* __restrict__ Wh2, unsigned short* __restrict__ Wl2,
                              unsigned short* __restrict__ Wh3, unsigned short* __restrict__ Wl3) {
    int i = blockIdx.x * blockDim.x + threadIdx.x;
    const float* W; unsigned short *Wh, *Wl; int K, F, off;
    if (i < 32768)                    { W = W0; Wh = Wh0; Wl = Wl0; K = 256; F = 128; off = i; }
    else if (i < 32768 + 16384)       { W = W1; Wh = Wh1; Wl = Wl1; K = 128; F = 128; off = i - 32768; }
    else if (i < 32768 + 32768)       { W = W2; Wh = Wh2; Wl = Wl2; K = 128; F = 128; off = i - 49152; }
    else if (i < 32768 + 32768 + 8192){ W = W3; Wh = Wh3; Wl = Wl3; K = 128; F = 64;  off = i - 65536; }
    else return;
    int k = off / F, c = off % F;
    unsigned short h, l;
    split_bf16(W[k * F + c], h, l);
    Wh[c * K + k] = h;
    Wl[c * K + k] = l;
}

// ---------------------------------------------------------------------------
// MFMA GEMM: H[m][c] = sum_k A[m][k]*W[k][c]; H stored fp16.
// 512 threads = 8 waves x 16-row strips (BM=128, KT=128, full-N). Same grid,
// LDS and traffic as the 4-wave version, 2x resident waves. Per-kt A-panel
// register prefetch (batched loads before the staging barrier). Each output
// element's MFMA k-order is identical to all prior versions (bit-exact).
// FA=true: A read from fp32 X, *onrm + bf16 split fused into the prefetch.
// ---------------------------------------------------------------------------
template <int K, int N, bool FA>
__global__ __launch_bounds__(512) void k_mm(const unsigned short* __restrict__ Ah,
                                            const unsigned short* __restrict__ Al,
                                            const float* __restrict__ Xf,
                                            const float* __restrict__ onrm,
                                            const unsigned short* __restrict__ Bh,
                                            const unsigned short* __restrict__ Bl,
                                            __half* __restrict__ H, int n) {
    constexpr int KT = 128;
    constexpr int NT = N / 16;
    constexpr int NKT = K / KT;
    __shared__ unsigned short sBh[N * KT];
    __shared__ unsigned short sBl[N * KT];

    int tid = threadIdx.x;
    int w = tid >> 6, lane = tid & 63;
    int quad = lane >> 4, l16 = lane & 15;
    int row_base = blockIdx.x * 128 + w * 16;   // 8 waves x 16 rows

    int ar0 = row_base + l16;
    if (ar0 >= n) ar0 = n - 1;

    float on0 = 0.f;
    if (FA) on0 = onrm[ar0];

    f32x4 acc[NT];
#pragma unroll
    for (int t = 0; t < NT; ++t) acc[t] = (f32x4){0.f, 0.f, 0.f, 0.f};

    for (int kt = 0; kt < NKT; ++kt) {
        // ---- A-panel register prefetch for this kt: batched independent loads
        short8 pa0h[4], pa0l[4];
        if (!FA) {
#pragma unroll
            for (int ph = 0; ph < 4; ++ph) {
                int eoff = kt * KT + ph * 32 + quad * 8;
                pa0h[ph] = *(const short8*)(Ah + (size_t)ar0 * K + eoff);
                pa0l[ph] = *(const short8*)(Al + (size_t)ar0 * K + eoff);
            }
        } else {
            float4 px0[8];
#pragma unroll
            for (int ph = 0; ph < 4; ++ph) {
                int eoff = kt * KT + ph * 32 + quad * 8;
                const float* x0 = Xf + (size_t)ar0 * K + eoff;
                px0[2 * ph]     = *(const float4*)x0;
                px0[2 * ph + 1] = *(const float4*)(x0 + 4);
            }
#pragma unroll
            for (int ph = 0; ph < 4; ++ph) {
                float e0[8] = {px0[2*ph].x, px0[2*ph].y, px0[2*ph].z, px0[2*ph].w,
                               px0[2*ph+1].x, px0[2*ph+1].y, px0[2*ph+1].z, px0[2*ph+1].w};
#pragma unroll
                for (int q = 0; q < 8; ++q) {
                    unsigned short hh, ll;
                    split_bf16(e0[q] * on0, hh, ll);
                    pa0h[ph][q] = (short)hh; pa0l[ph][q] = (short)ll;
                }
            }
        }

        if (kt) __syncthreads();
        for (int idx = tid; idx < N * 16; idx += 512) {
            int c = idx >> 4;
            int g = idx & 15;
            short8 vh = *(const short8*)(Bh + (size_t)c * K + kt * KT + g * 8);
            short8 vl = *(const short8*)(Bl + (size_t)c * K + kt * KT + g * 8);
            int sg = g ^ (c & 15);
            *(short8*)(&sBh[c * KT + sg * 8]) = vh;
            *(short8*)(&sBl[c * KT + sg * 8]) = vl;
        }
        __syncthreads();

#pragma unroll
        for (int k0 = 0; k0 < KT; k0 += 32) {
            int ph = k0 >> 5;                  // 0..3, static after unroll
            short8 a0hv = pa0h[ph], a0lv = pa0l[ph];
            int g = (k0 >> 3) + quad;
            int sg8 = (g ^ l16) * 8;
#pragma unroll
            for (int t = 0; t < NT; ++t) {
                int cb = (t * 16 + l16) * KT;
                short8 bh = *(const short8*)(&sBh[cb + sg8]);
                short8 bl = *(const short8*)(&sBl[cb + sg8]);
                acc[t] = __builtin_amdgcn_mfma_f32_16x16x32_bf16(a0hv, bh, acc[t], 0, 0, 0);
                acc[t] = __builtin_amdgcn_mfma_f32_16x16x32_bf16(a0lv, bh, acc[t], 0, 0, 0);
                acc[t] = __builtin_amdgcn_mfma_f32_16x16x32_bf16(a0hv, bl, acc[t], 0, 0, 0);
            }
        }
    }

#pragma unroll
    for (int t = 0; t < NT; ++t) {
#pragma unroll
        for (int r = 0; r < 4; ++r) {
            int grow = row_base + quad * 4 + r;
            if (grow < n) H[(size_t)grow * N + t * 16 + l16] = __float2half(acc[t][r]);
        }
    }
}

// ---------------------------------------------------------------------------
// Aggregation: 16-lane row segments, 4 nodes/wave (best-measured R2 config).
// ---------------------------------------------------------------------------

__global__ __launch_bounds__(256) void k_agg128_split(const __half* __restrict__ h,
                                                      const int* __restrict__ row_ptr,
                                                      const int* __restrict__ eidx,
                                                      const float* __restrict__ inrm,
                                                      const float* __restrict__ onrm,
                                                      const float* __restrict__ bias,
                                                      unsigned short* __restrict__ Ah,
                                                      unsigned short* __restrict__ Al, int n) {
    int wave = threadIdx.x >> 6;
    int lane = threadIdx.x & 63;
    int g = lane >> 4;
    int l = lane & 15;
    int node = blockIdx.x * 16 + wave * 4 + g;
    bool valid = node < n;
    int nd = valid ? node : n - 1;
    int beg = row_ptr[nd], end = row_ptr[nd + 1];
    const short8* h8 = (const short8*)h;   // row = 16 granules of 16B

    float a[4][8];
#pragma unroll
    for (int u = 0; u < 4; ++u)
#pragma unroll
        for (int c = 0; c < 8; ++c) a[u][c] = 0.f;

    int j = beg;
    for (; j + 4 <= end; j += 4) {
        int s[4];
#pragma unroll
        for (int u = 0; u < 4; ++u) s[u] = eidx[j + u];
        short8 v[4];
#pragma unroll
        for (int u = 0; u < 4; ++u) v[u] = h8[(size_t)s[u] * 16 + l];
#pragma unroll
        for (int u = 0; u < 4; ++u) {
            const __half2* ph = reinterpret_cast<const __half2*>(&v[u]);
#pragma unroll
            for (int p = 0; p < 4; ++p) {
                float2 f = __half22float2(ph[p]);
                a[u][2 * p] += f.x;
                a[u][2 * p + 1] += f.y;
            }
        }
    }
    for (; j < end; ++j) {
        short8 v = h8[(size_t)eidx[j] * 16 + l];
        const __half2* ph = reinterpret_cast<const __half2*>(&v);
#pragma unroll
        for (int p = 0; p < 4; ++p) {
            float2 f = __half22float2(ph[p]);
            a[0][2 * p] += f.x;
            a[0][2 * p + 1] += f.y;
        }
    }

    float nrm = inrm[nd];
    float on = onrm[nd];
    float4 b0 = ((const float4*)bias)[l * 2];
    float4 b1 = ((const float4*)bias)[l * 2 + 1];
    float bb[8] = {b0.x, b0.y, b0.z, b0.w, b1.x, b1.y, b1.z, b1.w};
    short8 hv, lv;
#pragma unroll
    for (int c = 0; c < 8; ++c) {
        float s = (a[0][c] + a[1][c]) + (a[2][c] + a[3][c]);
        float o = fmaxf(s * nrm + bb[c], 0.f) * on;
        unsigned short hh, ll;
        split_bf16(o, hh, ll);
        hv[c] = (short)hh;
        lv[c] = (short)ll;
    }
    if (valid) {
        ((short8*)Ah)[(size_t)node * 16 + l] = hv;
        ((short8*)Al)[(size_t)node * 16 + l] = lv;
    }
}

// FO=64 final layer: 16-lane x 8B segments (4 nodes/wave), unroll 8, fp32 out.
__global__ __launch_bounds__(256) void k_agg64(const __half* __restrict__ h,
                                               const int* __restrict__ row_ptr,
                                               const int* __restrict__ eidx,
                                               const float* __restrict__ inrm,
                                               const float* __restrict__ bias,
                                               float* __restrict__ out, int n) {
    int wave = threadIdx.x >> 6;
    int lane = threadIdx.x & 63;
    int g = lane >> 4;
    int l = lane & 15;
    int node = blockIdx.x * 16 + wave * 4 + g;
    bool valid = node < n;
    int nd = valid ? node : n - 1;
    int beg = row_ptr[nd], end = row_ptr[nd + 1];
    const ushort4* h4 = (const ushort4*)h;  // row = 16 granules of 8B

    float a[8][4];
#pragma unroll
    for (int u = 0; u < 8; ++u)
#pragma unroll
        for (int c = 0; c < 4; ++c) a[u][c] = 0.f;

    int j = beg;
    for (; j + 8 <= end; j += 8) {
        int s[8];
#pragma unroll
        for (int u = 0; u < 8; ++u) s[u] = eidx[j + u];
        ushort4 v[8];
#pragma unroll
        for (int u = 0; u < 8; ++u) v[u] = h4[(size_t)s[u] * 16 + l];
#pragma unroll
        for (int u = 0; u < 8; ++u) {
            const __half2* ph = reinterpret_cast<const __half2*>(&v[u]);
            float2 f0 = __half22float2(ph[0]);
            float2 f1 = __half22float2(ph[1]);
            a[u][0] += f0.x; a[u][1] += f0.y; a[u][2] += f1.x; a[u][3] += f1.y;
        }
    }
    for (; j < end; ++j) {
        ushort4 v = h4[(size_t)eidx[j] * 16 + l];
        const __half2* ph = reinterpret_cast<const __half2*>(&v);
        float2 f0 = __half22float2(ph[0]);
        float2 f1 = __half22float2(ph[1]);
        a[0][0] += f0.x; a[0][1] += f0.y; a[0][2] += f1.x; a[0][3] += f1.y;
    }

    float nrm = inrm[nd];
    float4 b4 = ((const float4*)bias)[l];
    float4 o;
    float s0 = ((a[0][0] + a[1][0]) + (a[2][0] + a[3][0])) + ((a[4][0] + a[5][0]) + (a[6][0] + a[7][0]));
    float s1 = ((a[0][1] + a[1][1]) + (a[2][1] + a[3][1])) + ((a[4][1] + a[5][1]) + (a[6][1] + a[7][1]));
    float s2 = ((a[0][2] + a[1][2]) + (a[2][2] + a[3][2])) + ((a[4][2] + a[5][2]) + (a[6][2] + a[7][2]));
    float s3 = ((a[0][3] + a[1][3]) + (a[2][3] + a[3][3])) + ((a[4][3] + a[5][3]) + (a[6][3] + a[7][3]));
    o.x = s0 * nrm + b4.x;
    o.y = s1 * nrm + b4.y;
    o.z = s2 * nrm + b4.z;
    o.w = s3 * nrm + b4.w;
    if (valid) ((float4*)out)[(size_t)node * 16 + l] = o;
}

// ---------------------------------------------------------------------------
// Legacy single-block scan (only for fallback path)
// ---------------------------------------------------------------------------
__global__ __launch_bounds__(1024) void k_scan(const int* __restrict__ deg, int n,
                                               int* __restrict__ row_ptr) {
    __shared__ int wsum[16];
    __shared__ int carry;
    int tid = threadIdx.x;
    int lane = tid & 63;
    int wid = tid >> 6;
    if (tid == 0) carry = 0;
    __syncthreads();
    int n4 = (n + 3) >> 2;
    for (int base = 0; base < n4; base += 1024) {
        int i4 = base + tid;
        int4 v = make_int4(0, 0, 0, 0);
        if (i4 < n4) v = ((const int4*)deg)[i4];
        int s = v.x + v.y + v.z + v.w;
        int x = s;
#pragma unroll
        for (int off = 1; off < 64; off <<= 1) {
            int y = __shfl_up(x, off, 64);
            if (lane >= off) x += y;
        }
        if (lane == 63) wsum[wid] = x;
        __syncthreads();
        if (wid == 0 && lane < 16) {
            int w = wsum[lane];
#pragma unroll
            for (int off = 1; off < 16; off <<= 1) {
                int y = __shfl_up(w, off, 16);
                if (lane >= off) w += y;
            }
            wsum[lane] = w;
        }
        __syncthreads();
        int excl = x - s + carry + (wid > 0 ? wsum[wid - 1] : 0);
        if (i4 < n4) {
            int e0 = excl, e1 = e0 + v.x, e2 = e1 + v.y, e3 = e2 + v.z;
            ((int4*)row_ptr)[i4] = make_int4(e0, e1, e2, e3);
        }
        __syncthreads();
        if (tid == 0) carry += wsum[15];
        __syncthreads();
    }
    if (tid == 0) row_ptr[n] = carry;
}

// ---------------------------------------------------------------------------
// Fallback fp32 path (known-good) — used if workspace too small for MFMA path.
// ---------------------------------------------------------------------------
template <int K, int FO, int TX, int TY, int RPT>
__global__ __launch_bounds__(256) void k_matmul(const float* __restrict__ X,
                                                const float* __restrict__ W,
                                                const float* __restrict__ onrm,
                                                float* __restrict__ H, int n) {
    constexpr int BROWS = TY * RPT;
    constexpr int LDK = K + 1;
    __shared__ float xs[BROWS * LDK];
    int tx = threadIdx.x, ty = threadIdx.y;
    int tid = ty * TX + tx;
    int row0 = blockIdx.x * BROWS;

    for (int idx = tid; idx < BROWS * K; idx += 256) {
        int r = idx / K;
        int k = idx - r * K;
        int row = row0 + r;
        xs[r * LDK + k] = (row < n) ? X[(size_t)row * K + k] : 0.f;
    }
    __syncthreads();

    float4 acc[RPT];
#pragma unroll
    for (int r = 0; r < RPT; ++r) acc[r] = make_float4(0.f, 0.f, 0.f, 0.f);

    const float4* W4 = (const float4*)W;
#pragma unroll 4
    for (int k = 0; k < K; ++k) {
        float4 w = W4[k * (FO / 4) + tx];
#pragma unroll
        for (int r = 0; r < RPT; ++r) {
            float xv = xs[(ty * RPT + r) * LDK + k];
            acc[r].x += xv * w.x;
            acc[r].y += xv * w.y;
            acc[r].z += xv * w.z;
            acc[r].w += xv * w.w;
        }
    }

#pragma unroll
    for (int r = 0; r < RPT; ++r) {
        int row = row0 + ty * RPT + r;
        if (row < n) {
            float s = onrm[row];
            float4 o = make_float4(acc[r].x * s, acc[r].y * s, acc[r].z * s, acc[r].w * s);
            ((float4*)H)[(size_t)row * (FO / 4) + tx] = o;
        }
    }
}

__global__ __launch_bounds__(256) void k_agg128f(const float* __restrict__ h,
                                                 const int* __restrict__ row_ptr,
                                                 const int* __restrict__ eidx,
                                                 const float* __restrict__ inrm,
                                                 const float* __restrict__ bias,
                                                 float* __restrict__ out, int n, int relu) {
    int node = blockIdx.x * 4 + (threadIdx.x >> 6);
    int lane = threadIdx.x & 63;
    if (node >= n) return;
    int beg = row_ptr[node], end = row_ptr[node + 1];
    const float2* h2 = (const float2*)h;
    float ax = 0.f, ay = 0.f;
    for (int j = beg; j < end; ++j) {
        int s = eidx[j];
        float2 v = h2[(size_t)s * 64 + lane];
        ax += v.x;
        ay += v.y;
    }
    float nrm = inrm[node];
    float2 b2 = ((const float2*)bias)[lane];
    float ox = ax * nrm + b2.x;
    float oy = ay * nrm + b2.y;
    if (relu) { ox = fmaxf(ox, 0.f); oy = fmaxf(oy, 0.f); }
    float2 o; o.x = ox; o.y = oy;
    ((float2*)out)[(size_t)node * 64 + lane] = o;
}

__global__ __launch_bounds__(256) void k_agg64f(const float* __restrict__ h,
                                                const int* __restrict__ row_ptr,
                                                const int* __restrict__ eidx,
                                                const float* __restrict__ inrm,
                                                const float* __restrict__ bias,
                                                float* __restrict__ out, int n) {
    int node = blockIdx.x * 4 + (threadIdx.x >> 6);
    int lane = threadIdx.x & 63;
    if (node >= n) return;
    int beg = row_ptr[node], end = row_ptr[node + 1];
    float acc = 0.f;
    for (int j = beg; j < end; ++j) {
        int s = eidx[j];
        acc += h[(size_t)s * 64 + lane];
    }
    out[(size_t)node * 64 + lane] = acc * inrm[node] + bias[lane];
}

// Legacy atomic preprocessing (fallback only)
__global__ void k_degrees_leg(const int* __restrict__ src, const int* __restrict__ dst,
                              int ne, int* __restrict__ degs, int* __restrict__ degd) {
    int i = blockIdx.x * blockDim.x + threadIdx.x;
    if (i < ne) {
        atomicAdd(&degs[src[i]], 1);
        atomicAdd(&degd[dst[i]], 1);
    }
}
__global__ void k_norms_leg(const int* __restrict__ degs, const int* __restrict__ degd,
                            float* __restrict__ onrm, float* __restrict__ inrm,
                            int* __restrict__ degd_sum, int n) {
    int i = blockIdx.x * blockDim.x + threadIdx.x;
    if (i < n) {
        degd_sum[i] = degd[i];
        onrm[i] = rsqrtf((float)max(degs[i], 1));
        inrm[i] = rsqrtf((float)max(degd[i], 1));
    }
}
__global__ void k_copy_int(const int* __restrict__ a, int* __restrict__ b, int n) {
    int i = blockIdx.x * blockDim.x + threadIdx.x;
    if (i < n) b[i] = a[i];
}
__global__ void k_build_csr_leg(const int* __restrict__ src, const int* __restrict__ dst,
                                int ne, int* __restrict__ cursor, int* __restrict__ eidx) {
    int i = blockIdx.x * blockDim.x + threadIdx.x;
    if (i < ne) {
        int p = atomicAdd(&cursor[dst[i]], 1);
        eidx[p] = src[i];
    }
}

static inline size_t align_up(size_t v, size_t a) { return (v + a - 1) & ~(a - 1); }

extern "C" void kernel_launch(void* const* d_in, const int* in_sizes, int n_in,
                              void* d_out, int out_size, void* d_ws, size_t ws_size,
                              hipStream_t stream) {
    const float* x  = (const float*)d_in[0];
    const int* ei   = (const int*)d_in[1];
    const float* W0 = (const float*)d_in[2];
    const float* b0 = (const float*)d_in[3];
    const float* W1 = (const float*)d_in[4];
    const float* b1 = (const float*)d_in[5];
    const float* W2 = (const float*)d_in[6];
    const float* b2 = (const float*)d_in[7];
    const float* W3 = (const float*)d_in[8];
    const float* b3 = (const float*)d_in[9];

    const int n  = in_sizes[0] / 256;   // 50000
    const int ne = in_sizes[1] / 2;     // 800000
    const int n_pad = (n + 127) & ~127;
    const int* src = ei;
    const int* dst = ei + ne;

    const int R = ((n + NRANGE * 64 - 1) / (NRANGE * 64)) * 64;   // 6272 for n=50000
    const int E = (ne + NCHUNK - 1) / NCHUNK;                     // 6250
    const int nscan = NRANGE * R;                                 // 50176
    const bool fast_pre = (R <= RMAX) && (E <= 65535);

    // ---- shared layout ----
    char* ws = (char*)d_ws;
    size_t off = 0;
    auto take = [&](size_t bytes) { void* p = ws + off; off = align_up(off + bytes, 256); return p; };
    int* row_ptr  = (int*)take((size_t)(nscan + 8) * 4);   // indexed to nscan by k_cursors2
    int* degd_sum = (int*)take((size_t)nscan * 4);         // indexed to nscan-1
    int* eidx     = (int*)take((size_t)ne * 4);
    float* onrm   = (float*)take((size_t)n * 4);
    float* inrm   = (float*)take((size_t)n * 4);

    // ---- MFMA-path layout ----
    size_t off_save = off;
    unsigned short* Ah  = (unsigned short*)take((size_t)n_pad * 256 * 2);
    unsigned short* Al  = (unsigned short*)take((size_t)n_pad * 256 * 2);
    __half* hbuf        = (__half*)take((size_t)n * 128 * 2);
    unsigned short* Wh0 = (unsigned short*)take(256 * 128 * 2);
    unsigned short* Wl0 = (unsigned short*)take(256 * 128 * 2);
    unsigned short* Wh1 = (unsigned short*)take(128 * 128 * 2);
    unsigned short* Wl1 = (unsigned short*)take(128 * 128 * 2);
    unsigned short* Wh2 = (unsigned short*)take(128 * 128 * 2);
    unsigned short* Wl2 = (unsigned short*)take(128 * 128 * 2);
    unsigned short* Wh3 = (unsigned short*)take(128 * 64 * 2);
    unsigned short* Wl3 = (unsigned short*)take(128 * 64 * 2);
    bool use_mfma = (off <= ws_size);

    // ---- preprocessing scratch ALIASED onto Ah/Al/hbuf (dead until mm0) ----
    char* pre = (char*)Ah;
    const size_t cntSz = align_up((size_t)NRANGE * NCHUNK * R * 2, 256);
    unsigned short* cnt_s = (unsigned short*)pre;
    unsigned short* cnt_d = (unsigned short*)(pre + cntSz);
    int* cbase            = (int*)(pre + 2 * cntSz);
    unsigned short* pos   = (unsigned short*)(pre + 4 * cntSz);
    int* blocksum         = (int*)(pre + 4 * cntSz + align_up((size_t)ne * 2, 256));

    const int aggGrid = (n + 15) / 16;

    if (fast_pre) {
        // ---- LDS-privatized preprocessing: zero global atomics ----
        const int nblk = nscan / 256;                   // 196 (<=256 required)
        const int wsplitBlocks = use_mfma ? 288 : 0;    // 73728/256
        k_hist<<<NRANGE * NCHUNK + wsplitBlocks, 256, 0, stream>>>(
            src, dst, ne, R, E, cnt_s, cnt_d, pos,
            W0, W1, W2, W3, Wh0, Wl0, Wh1, Wl1, Wh2, Wl2, Wh3, Wl3);
        k_reduce_norms<<<nblk, 256, 0, stream>>>(cnt_s, cnt_d, R, n,
                                                 onrm, inrm, degd_sum, blocksum);
        k_cursors2<<<nblk, 256, 0, stream>>>(blocksum, nblk, degd_sum, cnt_d, R,
                                             row_ptr, cbase, nscan);
        k_csr_scatter<<<(ne + 255) / 256, 256, 0, stream>>>(src, dst, pos, cbase, ne, R, E, eidx);
    } else {
        int* degs   = (int*)pre;
        int* degd   = (int*)pre + n_pad;
        int* cursor = (int*)pre + 2 * n_pad;
        hipMemsetAsync(degs, 0, (size_t)2 * n_pad * 4, stream);
        k_degrees_leg<<<(ne + 255) / 256, 256, 0, stream>>>(src, dst, ne, degs, degd);
        k_norms_leg<<<(n + 255) / 256, 256, 0, stream>>>(degs, degd, onrm, inrm, degd_sum, n);
        k_scan<<<1, 1024, 0, stream>>>(degd_sum, n, row_ptr);
        k_copy_int<<<(n + 255) / 256, 256, 0, stream>>>(row_ptr, cursor, n);
        k_build_csr_leg<<<(ne + 255) / 256, 256, 0, stream>>>(src, dst, ne, cursor, eidx);
        if (use_mfma)
            k_split_w_all<<<(73728 + 255) / 256, 256, 0, stream>>>(
                W0, W1, W2, W3, Wh0, Wl0, Wh1, Wl1, Wh2, Wl2, Wh3, Wl3);
    }

    if (use_mfma) {
        const int mmGrid = n_pad / 128;
        // L0: 256 -> 128, A = x fp32 (split fused, onrm folded)
        k_mm<256, 128, true><<<mmGrid, 512, 0, stream>>>(nullptr, nullptr, x, onrm, Wh0, Wl0, hbuf, n);
        k_agg128_split<<<aggGrid, 256, 0, stream>>>(hbuf, row_ptr, eidx, inrm, onrm, b0, Ah, Al, n);
        // L1
        k_mm<128, 128, false><<<mmGrid, 512, 0, stream>>>(Ah, Al, nullptr, nullptr, Wh1, Wl1, hbuf, n);
        k_agg128_split<<<aggGrid, 256, 0, stream>>>(hbuf, row_ptr, eidx, inrm, onrm, b1, Ah, Al, n);
        // L2
        k_mm<128, 128, false><<<mmGrid, 512, 0, stream>>>(Ah, Al, nullptr, nullptr, Wh2, Wl2, hbuf, n);
        k_agg128_split<<<aggGrid, 256, 0, stream>>>(hbuf, row_ptr, eidx, inrm, onrm, b2, Ah, Al, n);
        // L3: 128 -> 64
        k_mm<128, 64, false><<<mmGrid, 512, 0, stream>>>(Ah, Al, nullptr, nullptr, Wh3, Wl3, hbuf, n);
        k_agg64<<<aggGrid, 256, 0, stream>>>(hbuf, row_ptr, eidx, inrm, b3, (float*)d_out, n);
    } else {
        // fp32 fallback
        off = off_save;
        float* hbufF  = (float*)take((size_t)n * 128 * 4);
        float* xnextF = (float*)take((size_t)n * 128 * 4);
        const int aggGridF = (n + 3) / 4;

        k_matmul<256, 128, 32, 8, 4><<<(n + 31) / 32, dim3(32, 8), 0, stream>>>(x, W0, onrm, hbufF, n);
        k_agg128f<<<aggGridF, 256, 0, stream>>>(hbufF, row_ptr, eidx, inrm, b0, xnextF, n, 1);
        k_matmul<128, 128, 32, 8, 4><<<(n + 31) / 32, dim3(32, 8), 0, stream>>>(xnextF, W1, onrm, hbufF, n);
        k_agg128f<<<aggGridF, 256, 0, stream>>>(hbufF, row_ptr, eidx, inrm, b1, xnextF, n, 1);
        k_matmul<128, 128, 32, 8, 4><<<(n + 31) / 32, dim3(32, 8), 0, stream>>>(xnextF, W2, onrm, hbufF, n);
        k_agg128f<<<aggGridF, 256, 0, stream>>>(hbufF, row_ptr, eidx, inrm, b2, xnextF, n, 1);
        k_matmul<128, 64, 16, 16, 4><<<(n + 63) / 64, dim3(16, 16), 0, stream>>>(xnextF, W3, onrm, hbufF, n);
        k_agg64f<<<aggGridF, 256, 0, stream>>>(hbufF, row_ptr, eidx, inrm, b3, (float*)d_out, n);
    }
}